// Round 6
// baseline (359.510 us; speedup 1.0000x reference)
//
#include <hip/hip_runtime.h>
#include <stdint.h>
#include <stddef.h>

#define NNODES 50000
#define NEDGES 500000
#define DIM 256
#define NHEAD 8
#define HDIM 32
#define MPAD 50048   /* 391 * 128 */
#define NEGS 0.2f
#define SCAN_BLOCKS 196    /* ceil(50000/256) */
#define COUNT_BLOCKS 1954  /* ceil(500000/256) */
#define CVT_BLOCKS 12500   /* 50000*256/1024 */
#define TR_BLOCKS 192      /* 8*8*3 */
#define GEMM_BLOCKS 782    /* 391*2 */

typedef __attribute__((ext_vector_type(8))) short bf16x8;
typedef __attribute__((ext_vector_type(4))) float f32x4;
typedef __attribute__((ext_vector_type(4))) unsigned short u16x4;

__device__ __forceinline__ unsigned short f2bf(float f) {
    uint32_t u = __builtin_bit_cast(uint32_t, f);
    uint32_t r = (u + 0x7FFFu + ((u >> 16) & 1u)) >> 16;
    return (unsigned short)r;
}

__device__ __forceinline__ float bf2f(unsigned short u) {
    return __builtin_bit_cast(float, (uint32_t)u << 16);
}

__device__ __forceinline__ float bf2f_s(short u) {
    return __builtin_bit_cast(float, (uint32_t)(unsigned short)u << 16);
}

__device__ __forceinline__ float leaky(float x) {
    return x > 0.0f ? x : NEGS * x;
}

__device__ __forceinline__ void gld_lds16(const unsigned short* g, unsigned short* l) {
    __builtin_amdgcn_global_load_lds(
        (const __attribute__((address_space(1))) void*)g,
        (__attribute__((address_space(3))) void*)l,
        16, 0, 0);
}

// Bijective XCD pair-swizzle for 782 blocks over 8 XCDs (q=97, r=6).
// HW assigns XCD = dispatch_index % 8; this remap makes each XCD process a
// CONTIGUOUS run of virtual ids v, and maps v -> (bx=v>>1, by=v&1) so the two
// blocks sharing an A-panel (same bx) run on the SAME XCD back-to-back ->
// A-panel served from that XCD's L2 on the second use (~49 panels * 64KB
// fits 4MB L2). Perf-only; any bijection is correct.
__device__ __forceinline__ void xcd_pair(int orig, int& bx, int& by) {
    int x = orig & 7, g = orig >> 3;
    int v = (x < 6 ? x * 98 : 588 + (x - 6) * 97) + g;
    bx = v >> 1;
    by = v & 1;
}

// ---------------- CSR scan kernels (baseline, unchanged) ----------------

__global__ __launch_bounds__(256) void scanA_kernel(const int* __restrict__ deg,
                                                    int* __restrict__ bsum) {
    __shared__ int ws[4];
    int t = threadIdx.x;
    int idx = blockIdx.x * 256 + t;
    int v = (idx < NNODES) ? deg[idx] : 0;
    int x = v;
    #pragma unroll
    for (int off = 1; off < 64; off <<= 1) x += __shfl_xor(x, off, 64);
    if ((t & 63) == 0) ws[t >> 6] = x;
    __syncthreads();
    if (t == 0) bsum[blockIdx.x] = ws[0] + ws[1] + ws[2] + ws[3];
}

__global__ __launch_bounds__(256) void scanB_kernel(const int* __restrict__ bsum,
                                                    int* __restrict__ boff,
                                                    int* __restrict__ rowptr) {
    __shared__ int s[256];
    int t = threadIdx.x;
    int v = (t < SCAN_BLOCKS) ? bsum[t] : 0;
    s[t] = v;
    __syncthreads();
    #pragma unroll
    for (int off = 1; off < 256; off <<= 1) {
        int y = (t >= off) ? s[t - off] : 0;
        __syncthreads();
        s[t] += y;
        __syncthreads();
    }
    if (t < SCAN_BLOCKS) boff[t] = s[t] - v;  // exclusive
    if (t == 0) rowptr[NNODES] = NEDGES;
}

__global__ __launch_bounds__(256) void scanC_kernel(const int* __restrict__ deg,
                                                    const int* __restrict__ boff,
                                                    int* __restrict__ rowptr,
                                                    int* __restrict__ cursor) {
    __shared__ int ws[4];
    int t = threadIdx.x;
    int lane = t & 63, wv = t >> 6;
    int idx = blockIdx.x * 256 + t;
    int v = (idx < NNODES) ? deg[idx] : 0;
    int x = v;
    #pragma unroll
    for (int off = 1; off < 64; off <<= 1) {
        int y = __shfl_up(x, off, 64);
        if (lane >= off) x += y;
    }
    if (lane == 63) ws[wv] = x;
    __syncthreads();
    int wadd = 0;
    #pragma unroll
    for (int k = 0; k < 4; ++k) if (k < wv) wadd += ws[k];
    int excl = x - v + wadd + boff[blockIdx.x];
    if (idx < NNODES) { rowptr[idx] = excl; cursor[idx] = excl; }
}

// ---------------- combo1: count (atomic) + feats cvt (BW) + weight transpose ----------------

__global__ __launch_bounds__(256) void combo1(const int* __restrict__ dst,
                                              int* __restrict__ deg,
                                              const float* __restrict__ feats,
                                              unsigned short* __restrict__ Abf,
                                              const float* __restrict__ W0,
                                              const float* __restrict__ W1,
                                              const float* __restrict__ W2,
                                              unsigned short* __restrict__ WT) {
    __shared__ float tile[32][33];
    int b = blockIdx.x;
    if (b < COUNT_BLOCKS) {
        int i = b * 256 + threadIdx.x;
        if (i < NEDGES) atomicAdd(&deg[dst[i]], 1);
    } else if (b < COUNT_BLOCKS + CVT_BLOCKS) {
        int i = ((b - COUNT_BLOCKS) * 256 + threadIdx.x) * 4;
        const float4 v = *(const float4*)(feats + i);
        u16x4 o;
        o.x = f2bf(v.x); o.y = f2bf(v.y); o.z = f2bf(v.z); o.w = f2bf(v.w);
        *(u16x4*)(Abf + i) = o;
    } else {
        int t = b - COUNT_BLOCKS - CVT_BLOCKS;  // 0..191
        int bz = t >> 6;
        int bx = t & 7;          // n tile
        int by = (t >> 3) & 7;   // k tile
        const float* W = (bz == 0) ? W0 : (bz == 1) ? W1 : W2;
        unsigned short* T = WT + (size_t)bz * DIM * DIM;
        int tx = threadIdx.x & 31, ty = threadIdx.x >> 5;  // 32 x 8
        #pragma unroll
        for (int j = 0; j < 4; ++j)
            tile[ty + j * 8][tx] = W[(by * 32 + ty + j * 8) * DIM + bx * 32 + tx];
        __syncthreads();
        #pragma unroll
        for (int j = 0; j < 4; ++j)
            T[(bx * 32 + ty + j * 8) * DIM + by * 32 + tx] = f2bf(tile[tx][ty + j * 8]);
    }
}

// ---------------- GEMM body: pipelined BK=64, A via LDS dbuf, B direct from L2 ----------------
// Cb[M][256](bf16) = A[M][256](bf16) @ W (+bias), 128x128 tile.
// Changes vs the stage-all/drain/compute version:
//  - B fragments are loaded straight from BT (global). BT is 128 KB total ->
//    L2-resident; element mapping identical to the old LDS read
//    (n = col0+wn+j*16+fr, k-chunk = kk+kg). LDS halves to 32 KB -> 4 blocks/CU.
//  - A staged in BK=64 steps, double-buffered: the NEXT stage's 4 gld_lds are
//    issued BEFORE computing the current buffer, so the HBM latency overlaps
//    ds_read+MFMA+b-loads. One __syncthreads() (implicit vmcnt0 drain) per
//    K-step. T3-minimum 2-phase recipe; no inline asm.
// Buffer safety: stage at iter t writes buf[cur^1], whose last reader was
// iter t-1's compute, separated by the t-1 barrier. Reads at iter t consume
// data staged at t-1, drained by that same barrier.

__device__ __forceinline__ void gemm_body(int bx, int by,
        const unsigned short* __restrict__ A, const unsigned short* __restrict__ BT,
        unsigned short* __restrict__ Cb, const float* __restrict__ bias) {
    __shared__ __align__(16) unsigned short As2[2][2][128][32];  // 32 KB total
    int tid = threadIdx.x;
    int wave = tid >> 6, lane = tid & 63;
    int row0 = bx * 128;
    int col0 = by * 128;
    int wm = (wave >> 1) * 64;
    int wn = (wave & 1) * 64;

    f32x4 acc[4][4] = {};

    int fr = lane & 15;
    int kg = (lane >> 4) * 8;

    // per-thread staging coords (4 chunks of 16B per stage)
    // idx in [0,1024): c = k-32 chunk (0..1), row (0..127), q = 16B slot (0..3)
    // LDS offset idx*16B == As2[buf][c][row][q*8]; global k = kt*64 + c*32 + q*8
    const unsigned short* Bw = BT + (size_t)(col0 + wn + fr) * DIM + kg;

    #define STAGE(buf, kt)                                                        \
        do {                                                                      \
            _Pragma("unroll")                                                     \
            for (int r_ = 0; r_ < 4; ++r_) {                                      \
                int idx_ = r_ * 256 + tid;                                        \
                int c_ = idx_ >> 9;                                               \
                int rem_ = idx_ & 511;                                            \
                int row_ = rem_ >> 2;                                             \
                int q_ = rem_ & 3;                                                \
                gld_lds16(A + (size_t)(row0 + row_) * DIM + (kt) * 64 + c_ * 32 + q_ * 8, \
                          &As2[buf][0][0][0] + idx_ * 8);                         \
            }                                                                     \
        } while (0)

    STAGE(0, 0);
    __syncthreads();

    int cur = 0;
    #pragma unroll
    for (int t = 0; t < 4; ++t) {
        if (t < 3) STAGE(cur ^ 1, t + 1);
        #pragma unroll
        for (int c = 0; c < 2; ++c) {
            int kk = t * 64 + c * 32;
            bf16x8 a_frag[4], b_frag[4];
            #pragma unroll
            for (int i = 0; i < 4; ++i) {
                a_frag[i] = *(const bf16x8*)(&As2[cur][c][wm + i * 16 + fr][kg]);
                b_frag[i] = *(const bf16x8*)(Bw + (size_t)i * 16 * DIM + kk);
            }
            #pragma unroll
            for (int i = 0; i < 4; ++i)
                #pragma unroll
                for (int j = 0; j < 4; ++j)
                    acc[i][j] = __builtin_amdgcn_mfma_f32_16x16x32_bf16(
                        a_frag[i], b_frag[j], acc[i][j], 0, 0, 0);
        }
        if (t < 3) { __syncthreads(); cur ^= 1; }
    }
    #undef STAGE

    int rg = (lane >> 4) * 4;
    #pragma unroll
    for (int i = 0; i < 4; ++i) {
        #pragma unroll
        for (int j = 0; j < 4; ++j) {
            int n = col0 + wn + j * 16 + fr;
            float bv = bias ? bias[n] : 0.0f;
            #pragma unroll
            for (int r = 0; r < 4; ++r) {
                int m = row0 + wm + i * 16 + rg + r;
                Cb[(size_t)m * DIM + n] = f2bf(acc[i][j][r] + bv);
            }
        }
    }
}

__global__ __launch_bounds__(256) void gemm_kernel(const unsigned short* __restrict__ A,
                                                   const unsigned short* __restrict__ BT,
                                                   unsigned short* __restrict__ Cb,
                                                   const float* __restrict__ bias) {
    int bx, by;
    xcd_pair(blockIdx.x, bx, by);
    gemm_body(bx, by, A, BT, Cb, bias);
}

// ---------------- combo2: projection GEMM + CSR fill (independent outputs) ----------------

__global__ __launch_bounds__(256) void combo2(const unsigned short* __restrict__ A,
                                              const unsigned short* __restrict__ BT,
                                              unsigned short* __restrict__ Cb,
                                              const float* __restrict__ bias,
                                              const int* __restrict__ src,
                                              const int* __restrict__ dst,
                                              int* __restrict__ cursor,
                                              int* __restrict__ csr) {
    int b = blockIdx.x;
    if (b < GEMM_BLOCKS) {
        int bx, by;
        xcd_pair(b, bx, by);
        gemm_body(bx, by, A, BT, Cb, bias);
    } else {
        int i = (b - GEMM_BLOCKS) * 256 + threadIdx.x;
        if (i < NEDGES) {
            int pos = atomicAdd(&cursor[dst[i]], 1);
            csr[pos] = src[i];
        }
    }
}

// ---------------- el/er from bf16 h (separate kernel — fused epilogue measured
// SLOWER: 346.7 vs 340.0 us; 256 shfl/thread cost > 2 dispatches saved) --------

__global__ __launch_bounds__(256) void eler_kernel(const unsigned short* __restrict__ Hb,
                                                   const float* __restrict__ al,
                                                   const float* __restrict__ ar,
                                                   float* __restrict__ el,
                                                   float* __restrict__ er) {
    int wave = threadIdx.x >> 6;
    int lane = threadIdx.x & 63;
    int v = blockIdx.x * 4 + wave;
    if (v >= NNODES) return;
    int c0 = lane * 4;
    ushort4 h = *(const ushort4*)(Hb + (size_t)v * DIM + c0);
    float4 a = *(const float4*)(al + c0);
    float4 r = *(const float4*)(ar + c0);
    float h0 = bf2f(h.x), h1 = bf2f(h.y), h2 = bf2f(h.z), h3 = bf2f(h.w);
    float x = h0 * a.x + h1 * a.y + h2 * a.z + h3 * a.w;
    float y = h0 * r.x + h1 * r.y + h2 * r.z + h3 * r.w;
    #pragma unroll
    for (int off = 1; off < 8; off <<= 1) {
        x += __shfl_xor(x, off, 64);
        y += __shfl_xor(y, off, 64);
    }
    if ((lane & 7) == 0) {
        int head = lane >> 3;
        el[v * NHEAD + head] = x;
        er[v * NHEAD + head] = y;
    }
}

// ---------------- edge softmax + aggregation (round-0 proven form) ----------------
// One wave per dst node; 32 lanes per edge, 2 edges per iteration.
// NOTE: 4-edge shfl-broadcast variant measured SLOWER (52.5 vs 50.2 us).

__global__ __launch_bounds__(256) void agg_kernel(const unsigned short* __restrict__ Hb,
                                                  const float* __restrict__ el,
                                                  const float* __restrict__ er,
                                                  const int* __restrict__ rowptr,
                                                  const int* __restrict__ csr,
                                                  const float* __restrict__ bias,
                                                  float* __restrict__ outf,
                                                  unsigned short* __restrict__ outb) {
    int wave = threadIdx.x >> 6;
    int lane = threadIdx.x & 63;
    int v = blockIdx.x * 4 + wave;
    if (v >= NNODES) return;
    int sub = lane & 31;     // lane within half-wave
    int halfe = lane >> 5;   // which edge of the pair this half handles
    int c0 = sub * 8;        // dim offset (8 dims/lane)
    int head = sub >> 2;     // c0 / 32

    float er_v = er[v * NHEAD + head];
    float el_v = el[v * NHEAD + head];
    int beg = rowptr[v], end = rowptr[v + 1];

    float z = 0.0f;
    float acc[8] = {0.f, 0.f, 0.f, 0.f, 0.f, 0.f, 0.f, 0.f};

    // self loop on half 0 only
    if (halfe == 0) {
        float ws = __expf(leaky(el_v + er_v));
        z = ws;
        bf16x8 h = *(const bf16x8*)(Hb + (size_t)v * DIM + c0);
        #pragma unroll
        for (int d = 0; d < 8; ++d) acc[d] = ws * bf2f_s(h[d]);
    }

    #pragma unroll 4
    for (int i = beg + halfe; i < end; i += 2) {
        int u = csr[i];
        float e = leaky(el[u * NHEAD + head] + er_v);
        float wi = __expf(e);
        z += wi;
        bf16x8 h = *(const bf16x8*)(Hb + (size_t)u * DIM + c0);
        #pragma unroll
        for (int d = 0; d < 8; ++d) acc[d] += wi * bf2f_s(h[d]);
    }

    // cross-half reduction: both halves end with full totals
    z += __shfl_xor(z, 32, 64);
    #pragma unroll
    for (int d = 0; d < 8; ++d) acc[d] += __shfl_xor(acc[d], 32, 64);

    float inv = 1.0f / z;
    // each half stores 4 of the lane's 8 dims: half0 -> dims[0..3], half1 -> dims[4..7]
    int o0 = c0 + halfe * 4;
    float4 b = *(const float4*)(bias + o0);
    float r0 = leaky(acc[halfe * 4 + 0] * inv + b.x);
    float r1 = leaky(acc[halfe * 4 + 1] * inv + b.y);
    float r2 = leaky(acc[halfe * 4 + 2] * inv + b.z);
    float r3 = leaky(acc[halfe * 4 + 3] * inv + b.w);
    if (outf) {
        float4 o = { r0, r1, r2, r3 };
        *(float4*)(outf + (size_t)v * DIM + o0) = o;
    } else {
        u16x4 o;
        o.x = f2bf(r0); o.y = f2bf(r1); o.z = f2bf(r2); o.w = f2bf(r3);
        *(u16x4*)(outb + (size_t)v * DIM + o0) = o;
    }
}

// ---------------- launch ----------------

static inline size_t align256(size_t x) { return (x + 255) & ~(size_t)255; }

extern "C" void kernel_launch(void* const* d_in, const int* in_sizes, int n_in,
                              void* d_out, int out_size, void* d_ws, size_t ws_size,
                              hipStream_t stream) {
    const float* feats  = (const float*)d_in[0];
    const int*   src    = (const int*)d_in[1];
    const int*   dst    = (const int*)d_in[2];
    const float* proj_W = (const float*)d_in[3];
    const float* proj_b = (const float*)d_in[4];
    const float* W1     = (const float*)d_in[5];
    const float* al1    = (const float*)d_in[6];
    const float* ar1    = (const float*)d_in[7];
    const float* b1     = (const float*)d_in[8];
    const float* W2     = (const float*)d_in[9];
    const float* al2    = (const float*)d_in[10];
    const float* ar2    = (const float*)d_in[11];
    const float* b2     = (const float*)d_in[12];
    float* out = (float*)d_out;

    uint8_t* w = (uint8_t*)d_ws;
    unsigned short* Abf = (unsigned short*)w; w += align256((size_t)MPAD * DIM * 2);
    unsigned short* Bbf = (unsigned short*)w; w += align256((size_t)MPAD * DIM * 2);
    unsigned short* Hb  = (unsigned short*)w; w += align256((size_t)MPAD * DIM * 2);
    unsigned short* WT  = (unsigned short*)w; w += align256((size_t)3 * DIM * DIM * 2);
    float* el = (float*)w;            w += align256((size_t)NNODES * NHEAD * 4);
    float* er = (float*)w;            w += align256((size_t)NNODES * NHEAD * 4);
    int* deg    = (int*)w;            w += align256((size_t)NNODES * 4);
    int* rowptr = (int*)w;            w += align256((size_t)(NNODES + 1) * 4);
    int* cursor = (int*)w;            w += align256((size_t)NNODES * 4);
    int* csr    = (int*)w;            w += align256((size_t)NEDGES * 4);
    int* bsum   = (int*)w;            w += align256((size_t)SCAN_BLOCKS * 4);
    int* boff   = (int*)w;            w += align256((size_t)SCAN_BLOCKS * 4);

    unsigned short* WT0 = WT;
    unsigned short* WT1 = WT + (size_t)DIM * DIM;
    unsigned short* WT2 = WT + (size_t)2 * DIM * DIM;

    const int node_wave_blocks = (NNODES + 3) / 4;  // one wave per node

    hipMemsetAsync(deg, 0, (size_t)NNODES * 4, stream);

    // count + feats->bf16 + weight transpose, one dispatch
    combo1<<<COUNT_BLOCKS + CVT_BLOCKS + TR_BLOCKS, 256, 0, stream>>>(
        dst, deg, feats, Abf, proj_W, W1, W2, WT);

    scanA_kernel<<<SCAN_BLOCKS, 256, 0, stream>>>(deg, bsum);
    scanB_kernel<<<1, 256, 0, stream>>>(bsum, boff, rowptr);
    scanC_kernel<<<SCAN_BLOCKS, 256, 0, stream>>>(deg, boff, rowptr, cursor);

    // projection gemm + CSR fill, one dispatch
    combo2<<<GEMM_BLOCKS + COUNT_BLOCKS, 256, 0, stream>>>(
        Abf, WT0, Bbf, proj_b, src, dst, cursor, csr);

    // layer 1: Hb = Bbf @ W1 ; eler ; agg -> Abf (bf16)
    gemm_kernel<<<GEMM_BLOCKS, 256, 0, stream>>>(Bbf, WT1, Hb, nullptr);
    eler_kernel<<<node_wave_blocks, 256, 0, stream>>>(Hb, al1, ar1, el, er);
    agg_kernel<<<node_wave_blocks, 256, 0, stream>>>(Hb, el, er, rowptr, csr, b1,
                                                     nullptr, Abf);

    // layer 2: Hb = Abf @ W2 ; eler ; agg -> out (fp32)
    gemm_kernel<<<GEMM_BLOCKS, 256, 0, stream>>>(Abf, WT2, Hb, nullptr);
    eler_kernel<<<node_wave_blocks, 256, 0, stream>>>(Hb, al2, ar2, el, er);
    agg_kernel<<<node_wave_blocks, 256, 0, stream>>>(Hb, el, er, rowptr, csr, b2,
                                                     out, nullptr);
}

// Round 7
// 336.502 us; speedup vs baseline: 1.0684x; 1.0684x over previous
//
#include <hip/hip_runtime.h>
#include <stdint.h>
#include <stddef.h>

#define NNODES 50000
#define NEDGES 500000
#define DIM 256
#define NHEAD 8
#define HDIM 32
#define MPAD 50048   /* 391 * 128 */
#define NEGS 0.2f
#define SCAN_BLOCKS 196    /* ceil(50000/256) */
#define COUNT_BLOCKS 1954  /* ceil(500000/256) */
#define CVT_BLOCKS 12500   /* 50000*256/1024 */
#define TR_BLOCKS 192      /* 8*8*3 */
#define GEMM_BLOCKS 782    /* 391*2 */

typedef __attribute__((ext_vector_type(8))) short bf16x8;
typedef __attribute__((ext_vector_type(4))) float f32x4;
typedef __attribute__((ext_vector_type(4))) unsigned short u16x4;

__device__ __forceinline__ unsigned short f2bf(float f) {
    uint32_t u = __builtin_bit_cast(uint32_t, f);
    uint32_t r = (u + 0x7FFFu + ((u >> 16) & 1u)) >> 16;
    return (unsigned short)r;
}

__device__ __forceinline__ float bf2f(unsigned short u) {
    return __builtin_bit_cast(float, (uint32_t)u << 16);
}

__device__ __forceinline__ float bf2f_s(short u) {
    return __builtin_bit_cast(float, (uint32_t)(unsigned short)u << 16);
}

__device__ __forceinline__ float leaky(float x) {
    return x > 0.0f ? x : NEGS * x;
}

__device__ __forceinline__ void gld_lds16(const unsigned short* g, unsigned short* l) {
    __builtin_amdgcn_global_load_lds(
        (const __attribute__((address_space(1))) void*)g,
        (__attribute__((address_space(3))) void*)l,
        16, 0, 0);
}

// Bijective XCD pair-swizzle for 782 blocks over 8 XCDs (q=97, r=6).
// Makes the two blocks sharing an A-panel (same bx) run on the SAME XCD
// back-to-back -> A read ~once from HBM (r6 FETCH=15MB confirms). Perf-only.
__device__ __forceinline__ void xcd_pair(int orig, int& bx, int& by) {
    int x = orig & 7, g = orig >> 3;
    int v = (x < 6 ? x * 98 : 588 + (x - 6) * 97) + g;
    bx = v >> 1;
    by = v & 1;
}

// ---------------- CSR scan kernels (baseline, unchanged) ----------------

__global__ __launch_bounds__(256) void scanA_kernel(const int* __restrict__ deg,
                                                    int* __restrict__ bsum) {
    __shared__ int ws[4];
    int t = threadIdx.x;
    int idx = blockIdx.x * 256 + t;
    int v = (idx < NNODES) ? deg[idx] : 0;
    int x = v;
    #pragma unroll
    for (int off = 1; off < 64; off <<= 1) x += __shfl_xor(x, off, 64);
    if ((t & 63) == 0) ws[t >> 6] = x;
    __syncthreads();
    if (t == 0) bsum[blockIdx.x] = ws[0] + ws[1] + ws[2] + ws[3];
}

__global__ __launch_bounds__(256) void scanB_kernel(const int* __restrict__ bsum,
                                                    int* __restrict__ boff,
                                                    int* __restrict__ rowptr) {
    __shared__ int s[256];
    int t = threadIdx.x;
    int v = (t < SCAN_BLOCKS) ? bsum[t] : 0;
    s[t] = v;
    __syncthreads();
    #pragma unroll
    for (int off = 1; off < 256; off <<= 1) {
        int y = (t >= off) ? s[t - off] : 0;
        __syncthreads();
        s[t] += y;
        __syncthreads();
    }
    if (t < SCAN_BLOCKS) boff[t] = s[t] - v;  // exclusive
    if (t == 0) rowptr[NNODES] = NEDGES;
}

__global__ __launch_bounds__(256) void scanC_kernel(const int* __restrict__ deg,
                                                    const int* __restrict__ boff,
                                                    int* __restrict__ rowptr,
                                                    int* __restrict__ cursor) {
    __shared__ int ws[4];
    int t = threadIdx.x;
    int lane = t & 63, wv = t >> 6;
    int idx = blockIdx.x * 256 + t;
    int v = (idx < NNODES) ? deg[idx] : 0;
    int x = v;
    #pragma unroll
    for (int off = 1; off < 64; off <<= 1) {
        int y = __shfl_up(x, off, 64);
        if (lane >= off) x += y;
    }
    if (lane == 63) ws[wv] = x;
    __syncthreads();
    int wadd = 0;
    #pragma unroll
    for (int k = 0; k < 4; ++k) if (k < wv) wadd += ws[k];
    int excl = x - v + wadd + boff[blockIdx.x];
    if (idx < NNODES) { rowptr[idx] = excl; cursor[idx] = excl; }
}

// ---------------- combo1: count (atomic) + feats cvt (BW) + weight transpose ----------------

__global__ __launch_bounds__(256) void combo1(const int* __restrict__ dst,
                                              int* __restrict__ deg,
                                              const float* __restrict__ feats,
                                              unsigned short* __restrict__ Abf,
                                              const float* __restrict__ W0,
                                              const float* __restrict__ W1,
                                              const float* __restrict__ W2,
                                              unsigned short* __restrict__ WT) {
    __shared__ float tile[32][33];
    int b = blockIdx.x;
    if (b < COUNT_BLOCKS) {
        int i = b * 256 + threadIdx.x;
        if (i < NEDGES) atomicAdd(&deg[dst[i]], 1);
    } else if (b < COUNT_BLOCKS + CVT_BLOCKS) {
        int i = ((b - COUNT_BLOCKS) * 256 + threadIdx.x) * 4;
        const float4 v = *(const float4*)(feats + i);
        u16x4 o;
        o.x = f2bf(v.x); o.y = f2bf(v.y); o.z = f2bf(v.z); o.w = f2bf(v.w);
        *(u16x4*)(Abf + i) = o;
    } else {
        int t = b - COUNT_BLOCKS - CVT_BLOCKS;  // 0..191
        int bz = t >> 6;
        int bx = t & 7;          // n tile
        int by = (t >> 3) & 7;   // k tile
        const float* W = (bz == 0) ? W0 : (bz == 1) ? W1 : W2;
        unsigned short* T = WT + (size_t)bz * DIM * DIM;
        int tx = threadIdx.x & 31, ty = threadIdx.x >> 5;  // 32 x 8
        #pragma unroll
        for (int j = 0; j < 4; ++j)
            tile[ty + j * 8][tx] = W[(by * 32 + ty + j * 8) * DIM + bx * 32 + tx];
        __syncthreads();
        #pragma unroll
        for (int j = 0; j < 4; ++j)
            T[(bx * 32 + ty + j * 8) * DIM + by * 32 + tx] = f2bf(tile[tx][ty + j * 8]);
    }
}

// ---------------- GEMM body: BK=64 staging, 32 KB LDS -> 5 blocks/CU ----------------
// Cb[M][256](bf16) = A[M][256](bf16) @ W (+bias), 128x128 tile.
// Round-0 skeleton (stage -> sync -> compute -> sync), but K staged in FOUR
// 64-wide steps instead of two 128-wide: LDS 64KB -> 32KB, so 5 blocks/CU
// (was 2). The r6 profile showed the GEMM overlap-starved (MfmaUtil 3.7%,
// occupancy 25%, 1.2 TB/s): lockstep co-resident blocks all idle at the
// stage-drain barrier. 5 desynchronized blocks/CU restore cross-block
// stage/compute overlap. B stays LDS-staged (global-B variant regressed, r6).

__device__ __forceinline__ void gemm_body(int bx, int by,
        const unsigned short* __restrict__ A, const unsigned short* __restrict__ BT,
        unsigned short* __restrict__ Cb, const float* __restrict__ bias) {
    __shared__ __align__(16) unsigned short As[2][128][32];  // 16 KB
    __shared__ __align__(16) unsigned short Bs[2][128][32];  // 16 KB
    int tid = threadIdx.x;
    int wave = tid >> 6, lane = tid & 63;
    int row0 = bx * 128;
    int col0 = by * 128;
    int wm = (wave >> 1) * 64;
    int wn = (wave & 1) * 64;

    f32x4 acc[4][4] = {};

    int fr = lane & 15;
    int kg = (lane >> 4) * 8;

    #pragma unroll
    for (int kt = 0; kt < 4; ++kt) {
        // stage A and B for K = [kt*64, kt*64+64): each 128 rows x 64 K (16 KB)
        // idx in [0,1024): c = k-32 chunk, row, q = 16B slot; LDS dst idx*16B
        #pragma unroll
        for (int r = 0; r < 4; ++r) {
            int idx = r * 256 + tid;
            int c = idx >> 9;
            int rem = idx & 511;
            int row = rem >> 2;
            int q = rem & 3;
            gld_lds16(A + (size_t)(row0 + row) * DIM + kt * 64 + c * 32 + q * 8,
                      &As[0][0][0] + idx * 8);
            gld_lds16(BT + (size_t)(col0 + row) * DIM + kt * 64 + c * 32 + q * 8,
                      &Bs[0][0][0] + idx * 8);
        }
        __syncthreads();

        #pragma unroll
        for (int c = 0; c < 2; ++c) {
            bf16x8 a_frag[4], b_frag[4];
            #pragma unroll
            for (int i = 0; i < 4; ++i) {
                a_frag[i] = *(const bf16x8*)(&As[c][wm + i * 16 + fr][kg]);
                b_frag[i] = *(const bf16x8*)(&Bs[c][wn + i * 16 + fr][kg]);
            }
            #pragma unroll
            for (int i = 0; i < 4; ++i)
                #pragma unroll
                for (int j = 0; j < 4; ++j)
                    acc[i][j] = __builtin_amdgcn_mfma_f32_16x16x32_bf16(
                        a_frag[i], b_frag[j], acc[i][j], 0, 0, 0);
        }
        __syncthreads();
    }

    int rg = (lane >> 4) * 4;
    #pragma unroll
    for (int i = 0; i < 4; ++i) {
        #pragma unroll
        for (int j = 0; j < 4; ++j) {
            int n = col0 + wn + j * 16 + fr;
            float bv = bias ? bias[n] : 0.0f;
            #pragma unroll
            for (int r = 0; r < 4; ++r) {
                int m = row0 + wm + i * 16 + rg + r;
                Cb[(size_t)m * DIM + n] = f2bf(acc[i][j][r] + bv);
            }
        }
    }
}

__global__ __launch_bounds__(256) void gemm_kernel(const unsigned short* __restrict__ A,
                                                   const unsigned short* __restrict__ BT,
                                                   unsigned short* __restrict__ Cb,
                                                   const float* __restrict__ bias) {
    int bx, by;
    xcd_pair(blockIdx.x, bx, by);
    gemm_body(bx, by, A, BT, Cb, bias);
}

// ---------------- combo2: projection GEMM + CSR fill (independent outputs) ----------------

__global__ __launch_bounds__(256) void combo2(const unsigned short* __restrict__ A,
                                              const unsigned short* __restrict__ BT,
                                              unsigned short* __restrict__ Cb,
                                              const float* __restrict__ bias,
                                              const int* __restrict__ src,
                                              const int* __restrict__ dst,
                                              int* __restrict__ cursor,
                                              int* __restrict__ csr) {
    int b = blockIdx.x;
    if (b < GEMM_BLOCKS) {
        int bx, by;
        xcd_pair(b, bx, by);
        gemm_body(bx, by, A, BT, Cb, bias);
    } else {
        int i = (b - GEMM_BLOCKS) * 256 + threadIdx.x;
        if (i < NEDGES) {
            int pos = atomicAdd(&cursor[dst[i]], 1);
            csr[pos] = src[i];
        }
    }
}

// ---------------- el/er from bf16 h (separate kernel — fused epilogue measured
// SLOWER: 346.7 vs 340.0 us) ----------------

__global__ __launch_bounds__(256) void eler_kernel(const unsigned short* __restrict__ Hb,
                                                   const float* __restrict__ al,
                                                   const float* __restrict__ ar,
                                                   float* __restrict__ el,
                                                   float* __restrict__ er) {
    int wave = threadIdx.x >> 6;
    int lane = threadIdx.x & 63;
    int v = blockIdx.x * 4 + wave;
    if (v >= NNODES) return;
    int c0 = lane * 4;
    ushort4 h = *(const ushort4*)(Hb + (size_t)v * DIM + c0);
    float4 a = *(const float4*)(al + c0);
    float4 r = *(const float4*)(ar + c0);
    float h0 = bf2f(h.x), h1 = bf2f(h.y), h2 = bf2f(h.z), h3 = bf2f(h.w);
    float x = h0 * a.x + h1 * a.y + h2 * a.z + h3 * a.w;
    float y = h0 * r.x + h1 * r.y + h2 * r.z + h3 * r.w;
    #pragma unroll
    for (int off = 1; off < 8; off <<= 1) {
        x += __shfl_xor(x, off, 64);
        y += __shfl_xor(y, off, 64);
    }
    if ((lane & 7) == 0) {
        int head = lane >> 3;
        el[v * NHEAD + head] = x;
        er[v * NHEAD + head] = y;
    }
}

// ---------------- edge softmax + aggregation (round-0 proven form) ----------------
// One wave per dst node; 32 lanes per edge, 2 edges per iteration.
// NOTE: 4-edge shfl-broadcast variant measured SLOWER (52.5 vs 50.2 us/dispatch).

__global__ __launch_bounds__(256) void agg_kernel(const unsigned short* __restrict__ Hb,
                                                  const float* __restrict__ el,
                                                  const float* __restrict__ er,
                                                  const int* __restrict__ rowptr,
                                                  const int* __restrict__ csr,
                                                  const float* __restrict__ bias,
                                                  float* __restrict__ outf,
                                                  unsigned short* __restrict__ outb) {
    int wave = threadIdx.x >> 6;
    int lane = threadIdx.x & 63;
    int v = blockIdx.x * 4 + wave;
    if (v >= NNODES) return;
    int sub = lane & 31;     // lane within half-wave
    int halfe = lane >> 5;   // which edge of the pair this half handles
    int c0 = sub * 8;        // dim offset (8 dims/lane)
    int head = sub >> 2;     // c0 / 32

    float er_v = er[v * NHEAD + head];
    float el_v = el[v * NHEAD + head];
    int beg = rowptr[v], end = rowptr[v + 1];

    float z = 0.0f;
    float acc[8] = {0.f, 0.f, 0.f, 0.f, 0.f, 0.f, 0.f, 0.f};

    // self loop on half 0 only
    if (halfe == 0) {
        float ws = __expf(leaky(el_v + er_v));
        z = ws;
        bf16x8 h = *(const bf16x8*)(Hb + (size_t)v * DIM + c0);
        #pragma unroll
        for (int d = 0; d < 8; ++d) acc[d] = ws * bf2f_s(h[d]);
    }

    #pragma unroll 4
    for (int i = beg + halfe; i < end; i += 2) {
        int u = csr[i];
        float e = leaky(el[u * NHEAD + head] + er_v);
        float wi = __expf(e);
        z += wi;
        bf16x8 h = *(const bf16x8*)(Hb + (size_t)u * DIM + c0);
        #pragma unroll
        for (int d = 0; d < 8; ++d) acc[d] += wi * bf2f_s(h[d]);
    }

    // cross-half reduction: both halves end with full totals
    z += __shfl_xor(z, 32, 64);
    #pragma unroll
    for (int d = 0; d < 8; ++d) acc[d] += __shfl_xor(acc[d], 32, 64);

    float inv = 1.0f / z;
    // each half stores 4 of the lane's 8 dims: half0 -> dims[0..3], half1 -> dims[4..7]
    int o0 = c0 + halfe * 4;
    float4 b = *(const float4*)(bias + o0);
    float r0 = leaky(acc[halfe * 4 + 0] * inv + b.x);
    float r1 = leaky(acc[halfe * 4 + 1] * inv + b.y);
    float r2 = leaky(acc[halfe * 4 + 2] * inv + b.z);
    float r3 = leaky(acc[halfe * 4 + 3] * inv + b.w);
    if (outf) {
        float4 o = { r0, r1, r2, r3 };
        *(float4*)(outf + (size_t)v * DIM + o0) = o;
    } else {
        u16x4 o;
        o.x = f2bf(r0); o.y = f2bf(r1); o.z = f2bf(r2); o.w = f2bf(r3);
        *(u16x4*)(outb + (size_t)v * DIM + o0) = o;
    }
}

// ---------------- launch ----------------

static inline size_t align256(size_t x) { return (x + 255) & ~(size_t)255; }

extern "C" void kernel_launch(void* const* d_in, const int* in_sizes, int n_in,
                              void* d_out, int out_size, void* d_ws, size_t ws_size,
                              hipStream_t stream) {
    const float* feats  = (const float*)d_in[0];
    const int*   src    = (const int*)d_in[1];
    const int*   dst    = (const int*)d_in[2];
    const float* proj_W = (const float*)d_in[3];
    const float* proj_b = (const float*)d_in[4];
    const float* W1     = (const float*)d_in[5];
    const float* al1    = (const float*)d_in[6];
    const float* ar1    = (const float*)d_in[7];
    const float* b1     = (const float*)d_in[8];
    const float* W2     = (const float*)d_in[9];
    const float* al2    = (const float*)d_in[10];
    const float* ar2    = (const float*)d_in[11];
    const float* b2     = (const float*)d_in[12];
    float* out = (float*)d_out;

    uint8_t* w = (uint8_t*)d_ws;
    unsigned short* Abf = (unsigned short*)w; w += align256((size_t)MPAD * DIM * 2);
    unsigned short* Bbf = (unsigned short*)w; w += align256((size_t)MPAD * DIM * 2);
    unsigned short* Hb  = (unsigned short*)w; w += align256((size_t)MPAD * DIM * 2);
    unsigned short* WT  = (unsigned short*)w; w += align256((size_t)3 * DIM * DIM * 2);
    float* el = (float*)w;            w += align256((size_t)NNODES * NHEAD * 4);
    float* er = (float*)w;            w += align256((size_t)NNODES * NHEAD * 4);
    int* deg    = (int*)w;            w += align256((size_t)NNODES * 4);
    int* rowptr = (int*)w;            w += align256((size_t)(NNODES + 1) * 4);
    int* cursor = (int*)w;            w += align256((size_t)NNODES * 4);
    int* csr    = (int*)w;            w += align256((size_t)NEDGES * 4);
    int* bsum   = (int*)w;            w += align256((size_t)SCAN_BLOCKS * 4);
    int* boff   = (int*)w;            w += align256((size_t)SCAN_BLOCKS * 4);

    unsigned short* WT0 = WT;
    unsigned short* WT1 = WT + (size_t)DIM * DIM;
    unsigned short* WT2 = WT + (size_t)2 * DIM * DIM;

    const int node_wave_blocks = (NNODES + 3) / 4;  // one wave per node

    hipMemsetAsync(deg, 0, (size_t)NNODES * 4, stream);

    // count + feats->bf16 + weight transpose, one dispatch
    combo1<<<COUNT_BLOCKS + CVT_BLOCKS + TR_BLOCKS, 256, 0, stream>>>(
        dst, deg, feats, Abf, proj_W, W1, W2, WT);

    scanA_kernel<<<SCAN_BLOCKS, 256, 0, stream>>>(deg, bsum);
    scanB_kernel<<<1, 256, 0, stream>>>(bsum, boff, rowptr);
    scanC_kernel<<<SCAN_BLOCKS, 256, 0, stream>>>(deg, boff, rowptr, cursor);

    // projection gemm + CSR fill, one dispatch
    combo2<<<GEMM_BLOCKS + COUNT_BLOCKS, 256, 0, stream>>>(
        Abf, WT0, Bbf, proj_b, src, dst, cursor, csr);

    // layer 1: Hb = Bbf @ W1 ; eler ; agg -> Abf (bf16)
    gemm_kernel<<<GEMM_BLOCKS, 256, 0, stream>>>(Bbf, WT1, Hb, nullptr);
    eler_kernel<<<node_wave_blocks, 256, 0, stream>>>(Hb, al1, ar1, el, er);
    agg_kernel<<<node_wave_blocks, 256, 0, stream>>>(Hb, el, er, rowptr, csr, b1,
                                                     nullptr, Abf);

    // layer 2: Hb = Abf @ W2 ; eler ; agg -> out (fp32)
    gemm_kernel<<<GEMM_BLOCKS, 256, 0, stream>>>(Abf, WT2, Hb, nullptr);
    eler_kernel<<<node_wave_blocks, 256, 0, stream>>>(Hb, al2, ar2, el, er);
    agg_kernel<<<node_wave_blocks, 256, 0, stream>>>(Hb, el, er, rowptr, csr, b2,
                                                     out, nullptr);
}

// Round 8
// 321.685 us; speedup vs baseline: 1.1176x; 1.0461x over previous
//
#include <hip/hip_runtime.h>
#include <stdint.h>
#include <stddef.h>

#define NNODES 50000
#define NEDGES 500000
#define DIM 256
#define NHEAD 8
#define HDIM 32
#define MPAD 50048   /* 391 * 128 */
#define NEGS 0.2f
#define SCAN_BLOCKS 196    /* ceil(50000/256) */
#define COUNT_BLOCKS 1954  /* ceil(500000/256) */
#define CVT_BLOCKS 12500   /* 50000*256/1024 */
#define TR_BLOCKS 192      /* 8*8*3 */
#define GEMM_BLOCKS 782    /* 391*2 */

typedef __attribute__((ext_vector_type(8))) short bf16x8;
typedef __attribute__((ext_vector_type(4))) float f32x4;
typedef __attribute__((ext_vector_type(4))) unsigned short u16x4;

__device__ __forceinline__ unsigned short f2bf(float f) {
    uint32_t u = __builtin_bit_cast(uint32_t, f);
    uint32_t r = (u + 0x7FFFu + ((u >> 16) & 1u)) >> 16;
    return (unsigned short)r;
}

__device__ __forceinline__ float bf2f(unsigned short u) {
    return __builtin_bit_cast(float, (uint32_t)u << 16);
}

__device__ __forceinline__ float bf2f_s(short u) {
    return __builtin_bit_cast(float, (uint32_t)(unsigned short)u << 16);
}

__device__ __forceinline__ float leaky(float x) {
    return x > 0.0f ? x : NEGS * x;
}

__device__ __forceinline__ void gld_lds16(const unsigned short* g, unsigned short* l) {
    __builtin_amdgcn_global_load_lds(
        (const __attribute__((address_space(1))) void*)g,
        (__attribute__((address_space(3))) void*)l,
        16, 0, 0);
}

// Bijective XCD pair-swizzle for 782 blocks over 8 XCDs (q=97, r=6).
// Makes the two blocks sharing an A-panel (same bx) run on the SAME XCD
// back-to-back -> A read ~once from HBM (r6/r7 FETCH=15MB confirms). Perf-only.
__device__ __forceinline__ void xcd_pair(int orig, int& bx, int& by) {
    int x = orig & 7, g = orig >> 3;
    int v = (x < 6 ? x * 98 : 588 + (x - 6) * 97) + g;
    bx = v >> 1;
    by = v & 1;
}

// ---------------- CSR scan kernels (baseline, unchanged) ----------------

__global__ __launch_bounds__(256) void scanA_kernel(const int* __restrict__ deg,
                                                    int* __restrict__ bsum) {
    __shared__ int ws[4];
    int t = threadIdx.x;
    int idx = blockIdx.x * 256 + t;
    int v = (idx < NNODES) ? deg[idx] : 0;
    int x = v;
    #pragma unroll
    for (int off = 1; off < 64; off <<= 1) x += __shfl_xor(x, off, 64);
    if ((t & 63) == 0) ws[t >> 6] = x;
    __syncthreads();
    if (t == 0) bsum[blockIdx.x] = ws[0] + ws[1] + ws[2] + ws[3];
}

__global__ __launch_bounds__(256) void scanB_kernel(const int* __restrict__ bsum,
                                                    int* __restrict__ boff,
                                                    int* __restrict__ rowptr) {
    __shared__ int s[256];
    int t = threadIdx.x;
    int v = (t < SCAN_BLOCKS) ? bsum[t] : 0;
    s[t] = v;
    __syncthreads();
    #pragma unroll
    for (int off = 1; off < 256; off <<= 1) {
        int y = (t >= off) ? s[t - off] : 0;
        __syncthreads();
        s[t] += y;
        __syncthreads();
    }
    if (t < SCAN_BLOCKS) boff[t] = s[t] - v;  // exclusive
    if (t == 0) rowptr[NNODES] = NEDGES;
}

__global__ __launch_bounds__(256) void scanC_kernel(const int* __restrict__ deg,
                                                    const int* __restrict__ boff,
                                                    int* __restrict__ rowptr,
                                                    int* __restrict__ cursor) {
    __shared__ int ws[4];
    int t = threadIdx.x;
    int lane = t & 63, wv = t >> 6;
    int idx = blockIdx.x * 256 + t;
    int v = (idx < NNODES) ? deg[idx] : 0;
    int x = v;
    #pragma unroll
    for (int off = 1; off < 64; off <<= 1) {
        int y = __shfl_up(x, off, 64);
        if (lane >= off) x += y;
    }
    if (lane == 63) ws[wv] = x;
    __syncthreads();
    int wadd = 0;
    #pragma unroll
    for (int k = 0; k < 4; ++k) if (k < wv) wadd += ws[k];
    int excl = x - v + wadd + boff[blockIdx.x];
    if (idx < NNODES) { rowptr[idx] = excl; cursor[idx] = excl; }
}

// ---------------- combo1: count (atomic) + feats cvt (BW) + weight transpose ----------------

__global__ __launch_bounds__(256) void combo1(const int* __restrict__ dst,
                                              int* __restrict__ deg,
                                              const float* __restrict__ feats,
                                              unsigned short* __restrict__ Abf,
                                              const float* __restrict__ W0,
                                              const float* __restrict__ W1,
                                              const float* __restrict__ W2,
                                              unsigned short* __restrict__ WT) {
    __shared__ float tile[32][33];
    int b = blockIdx.x;
    if (b < COUNT_BLOCKS) {
        int i = b * 256 + threadIdx.x;
        if (i < NEDGES) atomicAdd(&deg[dst[i]], 1);
    } else if (b < COUNT_BLOCKS + CVT_BLOCKS) {
        int i = ((b - COUNT_BLOCKS) * 256 + threadIdx.x) * 4;
        const float4 v = *(const float4*)(feats + i);
        u16x4 o;
        o.x = f2bf(v.x); o.y = f2bf(v.y); o.z = f2bf(v.z); o.w = f2bf(v.w);
        *(u16x4*)(Abf + i) = o;
    } else {
        int t = b - COUNT_BLOCKS - CVT_BLOCKS;  // 0..191
        int bz = t >> 6;
        int bx = t & 7;          // n tile
        int by = (t >> 3) & 7;   // k tile
        const float* W = (bz == 0) ? W0 : (bz == 1) ? W1 : W2;
        unsigned short* T = WT + (size_t)bz * DIM * DIM;
        int tx = threadIdx.x & 31, ty = threadIdx.x >> 5;  // 32 x 8
        #pragma unroll
        for (int j = 0; j < 4; ++j)
            tile[ty + j * 8][tx] = W[(by * 32 + ty + j * 8) * DIM + bx * 32 + tx];
        __syncthreads();
        #pragma unroll
        for (int j = 0; j < 4; ++j)
            T[(bx * 32 + ty + j * 8) * DIM + by * 32 + tx] = f2bf(tile[tx][ty + j * 8]);
    }
}

// ---------------- GEMM body: BK=64 staging, 32 KB LDS ----------------
// Cb[M][256](bf16) = A[M][256](bf16) @ W (+bias), 128x128 tile.
// OCCUPANCY NOTE (r7 post-mortem): at 68 VGPR + 64 AGPR = 132 unified regs,
// occupancy sat at 2 waves/SIMD (24%) -- the 128-reg allocation boundary, not
// LDS, was binding. __launch_bounds__(256, 4) on the callers forces regs
// <= 128/wave (VGPR <= 64 with the 64-AGPR accumulator) -> 4 blocks/CU.

__device__ __forceinline__ void gemm_body(int bx, int by,
        const unsigned short* __restrict__ A, const unsigned short* __restrict__ BT,
        unsigned short* __restrict__ Cb, const float* __restrict__ bias) {
    __shared__ __align__(16) unsigned short As[2][128][32];  // 16 KB
    __shared__ __align__(16) unsigned short Bs[2][128][32];  // 16 KB
    int tid = threadIdx.x;
    int wave = tid >> 6, lane = tid & 63;
    int row0 = bx * 128;
    int col0 = by * 128;
    int wm = (wave >> 1) * 64;
    int wn = (wave & 1) * 64;

    f32x4 acc[4][4] = {};

    int fr = lane & 15;
    int kg = (lane >> 4) * 8;

    #pragma unroll
    for (int kt = 0; kt < 4; ++kt) {
        // stage A and B for K = [kt*64, kt*64+64): each 128 rows x 64 K (16 KB)
        #pragma unroll
        for (int r = 0; r < 4; ++r) {
            int idx = r * 256 + tid;
            int c = idx >> 9;
            int rem = idx & 511;
            int row = rem >> 2;
            int q = rem & 3;
            gld_lds16(A + (size_t)(row0 + row) * DIM + kt * 64 + c * 32 + q * 8,
                      &As[0][0][0] + idx * 8);
            gld_lds16(BT + (size_t)(col0 + row) * DIM + kt * 64 + c * 32 + q * 8,
                      &Bs[0][0][0] + idx * 8);
        }
        __syncthreads();

        #pragma unroll
        for (int c = 0; c < 2; ++c) {
            bf16x8 a_frag[4], b_frag[4];
            #pragma unroll
            for (int i = 0; i < 4; ++i) {
                a_frag[i] = *(const bf16x8*)(&As[c][wm + i * 16 + fr][kg]);
                b_frag[i] = *(const bf16x8*)(&Bs[c][wn + i * 16 + fr][kg]);
            }
            #pragma unroll
            for (int i = 0; i < 4; ++i)
                #pragma unroll
                for (int j = 0; j < 4; ++j)
                    acc[i][j] = __builtin_amdgcn_mfma_f32_16x16x32_bf16(
                        a_frag[i], b_frag[j], acc[i][j], 0, 0, 0);
        }
        __syncthreads();
    }

    int rg = (lane >> 4) * 4;
    #pragma unroll
    for (int i = 0; i < 4; ++i) {
        #pragma unroll
        for (int j = 0; j < 4; ++j) {
            int n = col0 + wn + j * 16 + fr;
            float bv = bias ? bias[n] : 0.0f;
            #pragma unroll
            for (int r = 0; r < 4; ++r) {
                int m = row0 + wm + i * 16 + rg + r;
                Cb[(size_t)m * DIM + n] = f2bf(acc[i][j][r] + bv);
            }
        }
    }
}

__global__ __launch_bounds__(256, 4) void gemm_kernel(const unsigned short* __restrict__ A,
                                                      const unsigned short* __restrict__ BT,
                                                      unsigned short* __restrict__ Cb,
                                                      const float* __restrict__ bias) {
    int bx, by;
    xcd_pair(blockIdx.x, bx, by);
    gemm_body(bx, by, A, BT, Cb, bias);
}

// ---------------- combo2: projection GEMM + CSR fill (independent outputs) ----------------

__global__ __launch_bounds__(256, 4) void combo2(const unsigned short* __restrict__ A,
                                                 const unsigned short* __restrict__ BT,
                                                 unsigned short* __restrict__ Cb,
                                                 const float* __restrict__ bias,
                                                 const int* __restrict__ src,
                                                 const int* __restrict__ dst,
                                                 int* __restrict__ cursor,
                                                 int* __restrict__ csr) {
    int b = blockIdx.x;
    if (b < GEMM_BLOCKS) {
        int bx, by;
        xcd_pair(b, bx, by);
        gemm_body(bx, by, A, BT, Cb, bias);
    } else {
        int i = (b - GEMM_BLOCKS) * 256 + threadIdx.x;
        if (i < NEDGES) {
            int pos = atomicAdd(&cursor[dst[i]], 1);
            csr[pos] = src[i];
        }
    }
}

// ---------------- el/er from bf16 h (separate kernel — fused epilogue measured
// SLOWER: 346.7 vs 340.0 us) ----------------

__global__ __launch_bounds__(256) void eler_kernel(const unsigned short* __restrict__ Hb,
                                                   const float* __restrict__ al,
                                                   const float* __restrict__ ar,
                                                   float* __restrict__ el,
                                                   float* __restrict__ er) {
    int wave = threadIdx.x >> 6;
    int lane = threadIdx.x & 63;
    int v = blockIdx.x * 4 + wave;
    if (v >= NNODES) return;
    int c0 = lane * 4;
    ushort4 h = *(const ushort4*)(Hb + (size_t)v * DIM + c0);
    float4 a = *(const float4*)(al + c0);
    float4 r = *(const float4*)(ar + c0);
    float h0 = bf2f(h.x), h1 = bf2f(h.y), h2 = bf2f(h.z), h3 = bf2f(h.w);
    float x = h0 * a.x + h1 * a.y + h2 * a.z + h3 * a.w;
    float y = h0 * r.x + h1 * r.y + h2 * r.z + h3 * r.w;
    #pragma unroll
    for (int off = 1; off < 8; off <<= 1) {
        x += __shfl_xor(x, off, 64);
        y += __shfl_xor(y, off, 64);
    }
    if ((lane & 7) == 0) {
        int head = lane >> 3;
        el[v * NHEAD + head] = x;
        er[v * NHEAD + head] = y;
    }
}

// ---------------- edge softmax + aggregation (round-0 proven form) ----------------
// One wave per dst node; 32 lanes per edge, 2 edges per iteration.
// NOTE: 4-edge shfl-broadcast variant measured SLOWER (52.5 vs 50.2 us/dispatch).

__global__ __launch_bounds__(256) void agg_kernel(const unsigned short* __restrict__ Hb,
                                                  const float* __restrict__ el,
                                                  const float* __restrict__ er,
                                                  const int* __restrict__ rowptr,
                                                  const int* __restrict__ csr,
                                                  const float* __restrict__ bias,
                                                  float* __restrict__ outf,
                                                  unsigned short* __restrict__ outb) {
    int wave = threadIdx.x >> 6;
    int lane = threadIdx.x & 63;
    int v = blockIdx.x * 4 + wave;
    if (v >= NNODES) return;
    int sub = lane & 31;     // lane within half-wave
    int halfe = lane >> 5;   // which edge of the pair this half handles
    int c0 = sub * 8;        // dim offset (8 dims/lane)
    int head = sub >> 2;     // c0 / 32

    float er_v = er[v * NHEAD + head];
    float el_v = el[v * NHEAD + head];
    int beg = rowptr[v], end = rowptr[v + 1];

    float z = 0.0f;
    float acc[8] = {0.f, 0.f, 0.f, 0.f, 0.f, 0.f, 0.f, 0.f};

    // self loop on half 0 only
    if (halfe == 0) {
        float ws = __expf(leaky(el_v + er_v));
        z = ws;
        bf16x8 h = *(const bf16x8*)(Hb + (size_t)v * DIM + c0);
        #pragma unroll
        for (int d = 0; d < 8; ++d) acc[d] = ws * bf2f_s(h[d]);
    }

    #pragma unroll 4
    for (int i = beg + halfe; i < end; i += 2) {
        int u = csr[i];
        float e = leaky(el[u * NHEAD + head] + er_v);
        float wi = __expf(e);
        z += wi;
        bf16x8 h = *(const bf16x8*)(Hb + (size_t)u * DIM + c0);
        #pragma unroll
        for (int d = 0; d < 8; ++d) acc[d] += wi * bf2f_s(h[d]);
    }

    // cross-half reduction: both halves end with full totals
    z += __shfl_xor(z, 32, 64);
    #pragma unroll
    for (int d = 0; d < 8; ++d) acc[d] += __shfl_xor(acc[d], 32, 64);

    float inv = 1.0f / z;
    // each half stores 4 of the lane's 8 dims: half0 -> dims[0..3], half1 -> dims[4..7]
    int o0 = c0 + halfe * 4;
    float4 b = *(const float4*)(bias + o0);
    float r0 = leaky(acc[halfe * 4 + 0] * inv + b.x);
    float r1 = leaky(acc[halfe * 4 + 1] * inv + b.y);
    float r2 = leaky(acc[halfe * 4 + 2] * inv + b.z);
    float r3 = leaky(acc[halfe * 4 + 3] * inv + b.w);
    if (outf) {
        float4 o = { r0, r1, r2, r3 };
        *(float4*)(outf + (size_t)v * DIM + o0) = o;
    } else {
        u16x4 o;
        o.x = f2bf(r0); o.y = f2bf(r1); o.z = f2bf(r2); o.w = f2bf(r3);
        *(u16x4*)(outb + (size_t)v * DIM + o0) = o;
    }
}

// ---------------- launch ----------------

static inline size_t align256(size_t x) { return (x + 255) & ~(size_t)255; }

extern "C" void kernel_launch(void* const* d_in, const int* in_sizes, int n_in,
                              void* d_out, int out_size, void* d_ws, size_t ws_size,
                              hipStream_t stream) {
    const float* feats  = (const float*)d_in[0];
    const int*   src    = (const int*)d_in[1];
    const int*   dst    = (const int*)d_in[2];
    const float* proj_W = (const float*)d_in[3];
    const float* proj_b = (const float*)d_in[4];
    const float* W1     = (const float*)d_in[5];
    const float* al1    = (const float*)d_in[6];
    const float* ar1    = (const float*)d_in[7];
    const float* b1     = (const float*)d_in[8];
    const float* W2     = (const float*)d_in[9];
    const float* al2    = (const float*)d_in[10];
    const float* ar2    = (const float*)d_in[11];
    const float* b2     = (const float*)d_in[12];
    float* out = (float*)d_out;

    uint8_t* w = (uint8_t*)d_ws;
    unsigned short* Abf = (unsigned short*)w; w += align256((size_t)MPAD * DIM * 2);
    unsigned short* Bbf = (unsigned short*)w; w += align256((size_t)MPAD * DIM * 2);
    unsigned short* Hb  = (unsigned short*)w; w += align256((size_t)MPAD * DIM * 2);
    unsigned short* WT  = (unsigned short*)w; w += align256((size_t)3 * DIM * DIM * 2);
    float* el = (float*)w;            w += align256((size_t)NNODES * NHEAD * 4);
    float* er = (float*)w;            w += align256((size_t)NNODES * NHEAD * 4);
    int* deg    = (int*)w;            w += align256((size_t)NNODES * 4);
    int* rowptr = (int*)w;            w += align256((size_t)(NNODES + 1) * 4);
    int* cursor = (int*)w;            w += align256((size_t)NNODES * 4);
    int* csr    = (int*)w;            w += align256((size_t)NEDGES * 4);
    int* bsum   = (int*)w;            w += align256((size_t)SCAN_BLOCKS * 4);
    int* boff   = (int*)w;            w += align256((size_t)SCAN_BLOCKS * 4);

    unsigned short* WT0 = WT;
    unsigned short* WT1 = WT + (size_t)DIM * DIM;
    unsigned short* WT2 = WT + (size_t)2 * DIM * DIM;

    const int node_wave_blocks = (NNODES + 3) / 4;  // one wave per node

    hipMemsetAsync(deg, 0, (size_t)NNODES * 4, stream);

    // count + feats->bf16 + weight transpose, one dispatch
    combo1<<<COUNT_BLOCKS + CVT_BLOCKS + TR_BLOCKS, 256, 0, stream>>>(
        dst, deg, feats, Abf, proj_W, W1, W2, WT);

    scanA_kernel<<<SCAN_BLOCKS, 256, 0, stream>>>(deg, bsum);
    scanB_kernel<<<1, 256, 0, stream>>>(bsum, boff, rowptr);
    scanC_kernel<<<SCAN_BLOCKS, 256, 0, stream>>>(deg, boff, rowptr, cursor);

    // projection gemm + CSR fill, one dispatch
    combo2<<<GEMM_BLOCKS + COUNT_BLOCKS, 256, 0, stream>>>(
        Abf, WT0, Bbf, proj_b, src, dst, cursor, csr);

    // layer 1: Hb = Bbf @ W1 ; eler ; agg -> Abf (bf16)
    gemm_kernel<<<GEMM_BLOCKS, 256, 0, stream>>>(Bbf, WT1, Hb, nullptr);
    eler_kernel<<<node_wave_blocks, 256, 0, stream>>>(Hb, al1, ar1, el, er);
    agg_kernel<<<node_wave_blocks, 256, 0, stream>>>(Hb, el, er, rowptr, csr, b1,
                                                     nullptr, Abf);

    // layer 2: Hb = Abf @ W2 ; eler ; agg -> out (fp32)
    gemm_kernel<<<GEMM_BLOCKS, 256, 0, stream>>>(Abf, WT2, Hb, nullptr);
    eler_kernel<<<node_wave_blocks, 256, 0, stream>>>(Hb, al2, ar2, el, er);
    agg_kernel<<<node_wave_blocks, 256, 0, stream>>>(Hb, el, er, rowptr, csr, b2,
                                                     out, nullptr);
}

// Round 9
// 310.793 us; speedup vs baseline: 1.1568x; 1.0350x over previous
//
#include <hip/hip_runtime.h>
#include <stdint.h>
#include <stddef.h>

#define NNODES 50000
#define NEDGES 500000
#define DIM 256
#define NHEAD 8
#define HDIM 32
#define MPAD 50048   /* 391 * 128 */
#define NEGS 0.2f
#define SCAN_BLOCKS 196    /* ceil(50000/256) */
#define COUNT_BLOCKS 1954  /* ceil(500000/256) */
#define CVT_BLOCKS 12500   /* 50000*256/1024 */
#define TR_BLOCKS 192      /* 8*8*3 */
#define GEMM_BLOCKS 782    /* 391*2 */

typedef __attribute__((ext_vector_type(8))) short bf16x8;
typedef __attribute__((ext_vector_type(4))) float f32x4;
typedef __attribute__((ext_vector_type(4))) unsigned short u16x4;

__device__ __forceinline__ unsigned short f2bf(float f) {
    uint32_t u = __builtin_bit_cast(uint32_t, f);
    uint32_t r = (u + 0x7FFFu + ((u >> 16) & 1u)) >> 16;
    return (unsigned short)r;
}

__device__ __forceinline__ float bf2f(unsigned short u) {
    return __builtin_bit_cast(float, (uint32_t)u << 16);
}

__device__ __forceinline__ float bf2f_s(short u) {
    return __builtin_bit_cast(float, (uint32_t)(unsigned short)u << 16);
}

__device__ __forceinline__ float leaky(float x) {
    return x > 0.0f ? x : NEGS * x;
}

__device__ __forceinline__ void gld_lds16(const unsigned short* g, unsigned short* l) {
    __builtin_amdgcn_global_load_lds(
        (const __attribute__((address_space(1))) void*)g,
        (__attribute__((address_space(3))) void*)l,
        16, 0, 0);
}

// Bijective XCD pair-swizzle for 782 blocks over 8 XCDs (q=97, r=6).
// Makes the two blocks sharing an A-panel (same bx) run on the SAME XCD
// back-to-back -> A read ~once from HBM (r6/r7 FETCH=15MB confirms). Perf-only.
__device__ __forceinline__ void xcd_pair(int orig, int& bx, int& by) {
    int x = orig & 7, g = orig >> 3;
    int v = (x < 6 ? x * 98 : 588 + (x - 6) * 97) + g;
    bx = v >> 1;
    by = v & 1;
}

// ---------------- CSR scan kernels (baseline, unchanged) ----------------

__global__ __launch_bounds__(256) void scanA_kernel(const int* __restrict__ deg,
                                                    int* __restrict__ bsum) {
    __shared__ int ws[4];
    int t = threadIdx.x;
    int idx = blockIdx.x * 256 + t;
    int v = (idx < NNODES) ? deg[idx] : 0;
    int x = v;
    #pragma unroll
    for (int off = 1; off < 64; off <<= 1) x += __shfl_xor(x, off, 64);
    if ((t & 63) == 0) ws[t >> 6] = x;
    __syncthreads();
    if (t == 0) bsum[blockIdx.x] = ws[0] + ws[1] + ws[2] + ws[3];
}

__global__ __launch_bounds__(256) void scanB_kernel(const int* __restrict__ bsum,
                                                    int* __restrict__ boff,
                                                    int* __restrict__ rowptr) {
    __shared__ int s[256];
    int t = threadIdx.x;
    int v = (t < SCAN_BLOCKS) ? bsum[t] : 0;
    s[t] = v;
    __syncthreads();
    #pragma unroll
    for (int off = 1; off < 256; off <<= 1) {
        int y = (t >= off) ? s[t - off] : 0;
        __syncthreads();
        s[t] += y;
        __syncthreads();
    }
    if (t < SCAN_BLOCKS) boff[t] = s[t] - v;  // exclusive
    if (t == 0) rowptr[NNODES] = NEDGES;
}

__global__ __launch_bounds__(256) void scanC_kernel(const int* __restrict__ deg,
                                                    const int* __restrict__ boff,
                                                    int* __restrict__ rowptr,
                                                    int* __restrict__ cursor) {
    __shared__ int ws[4];
    int t = threadIdx.x;
    int lane = t & 63, wv = t >> 6;
    int idx = blockIdx.x * 256 + t;
    int v = (idx < NNODES) ? deg[idx] : 0;
    int x = v;
    #pragma unroll
    for (int off = 1; off < 64; off <<= 1) {
        int y = __shfl_up(x, off, 64);
        if (lane >= off) x += y;
    }
    if (lane == 63) ws[wv] = x;
    __syncthreads();
    int wadd = 0;
    #pragma unroll
    for (int k = 0; k < 4; ++k) if (k < wv) wadd += ws[k];
    int excl = x - v + wadd + boff[blockIdx.x];
    if (idx < NNODES) { rowptr[idx] = excl; cursor[idx] = excl; }
}

// ---------------- combo1: count (atomic) + feats cvt (BW) + weight transpose ----------------

__global__ __launch_bounds__(256) void combo1(const int* __restrict__ dst,
                                              int* __restrict__ deg,
                                              const float* __restrict__ feats,
                                              unsigned short* __restrict__ Abf,
                                              const float* __restrict__ W0,
                                              const float* __restrict__ W1,
                                              const float* __restrict__ W2,
                                              unsigned short* __restrict__ WT) {
    __shared__ float tile[32][33];
    int b = blockIdx.x;
    if (b < COUNT_BLOCKS) {
        int i = b * 256 + threadIdx.x;
        if (i < NEDGES) atomicAdd(&deg[dst[i]], 1);
    } else if (b < COUNT_BLOCKS + CVT_BLOCKS) {
        int i = ((b - COUNT_BLOCKS) * 256 + threadIdx.x) * 4;
        const float4 v = *(const float4*)(feats + i);
        u16x4 o;
        o.x = f2bf(v.x); o.y = f2bf(v.y); o.z = f2bf(v.z); o.w = f2bf(v.w);
        *(u16x4*)(Abf + i) = o;
    } else {
        int t = b - COUNT_BLOCKS - CVT_BLOCKS;  // 0..191
        int bz = t >> 6;
        int bx = t & 7;          // n tile
        int by = (t >> 3) & 7;   // k tile
        const float* W = (bz == 0) ? W0 : (bz == 1) ? W1 : W2;
        unsigned short* T = WT + (size_t)bz * DIM * DIM;
        int tx = threadIdx.x & 31, ty = threadIdx.x >> 5;  // 32 x 8
        #pragma unroll
        for (int j = 0; j < 4; ++j)
            tile[ty + j * 8][tx] = W[(by * 32 + ty + j * 8) * DIM + bx * 32 + tx];
        __syncthreads();
        #pragma unroll
        for (int j = 0; j < 4; ++j)
            T[(bx * 32 + ty + j * 8) * DIM + by * 32 + tx] = f2bf(tile[tx][ty + j * 8]);
    }
}

// ---------------- GEMM body: BK=64 staging, 32 KB LDS, 4 blocks/CU ----------------
// Cb[M][256](bf16) = A[M][256](bf16) @ W (+bias), 128x128 tile.
// __launch_bounds__(256,4): at 68 VGPR + 64 AGPR = 132 unified regs the HW
// allocated the 256-reg class -> 2 waves/SIMD (24% occ, r7). Forcing
// regs <= 128/wave doubled co-resident blocks -> r8 = -14.8 us. Keep.

__device__ __forceinline__ void gemm_body(int bx, int by,
        const unsigned short* __restrict__ A, const unsigned short* __restrict__ BT,
        unsigned short* __restrict__ Cb, const float* __restrict__ bias) {
    __shared__ __align__(16) unsigned short As[2][128][32];  // 16 KB
    __shared__ __align__(16) unsigned short Bs[2][128][32];  // 16 KB
    int tid = threadIdx.x;
    int wave = tid >> 6, lane = tid & 63;
    int row0 = bx * 128;
    int col0 = by * 128;
    int wm = (wave >> 1) * 64;
    int wn = (wave & 1) * 64;

    f32x4 acc[4][4] = {};

    int fr = lane & 15;
    int kg = (lane >> 4) * 8;

    #pragma unroll
    for (int kt = 0; kt < 4; ++kt) {
        #pragma unroll
        for (int r = 0; r < 4; ++r) {
            int idx = r * 256 + tid;
            int c = idx >> 9;
            int rem = idx & 511;
            int row = rem >> 2;
            int q = rem & 3;
            gld_lds16(A + (size_t)(row0 + row) * DIM + kt * 64 + c * 32 + q * 8,
                      &As[0][0][0] + idx * 8);
            gld_lds16(BT + (size_t)(col0 + row) * DIM + kt * 64 + c * 32 + q * 8,
                      &Bs[0][0][0] + idx * 8);
        }
        __syncthreads();

        #pragma unroll
        for (int c = 0; c < 2; ++c) {
            bf16x8 a_frag[4], b_frag[4];
            #pragma unroll
            for (int i = 0; i < 4; ++i) {
                a_frag[i] = *(const bf16x8*)(&As[c][wm + i * 16 + fr][kg]);
                b_frag[i] = *(const bf16x8*)(&Bs[c][wn + i * 16 + fr][kg]);
            }
            #pragma unroll
            for (int i = 0; i < 4; ++i)
                #pragma unroll
                for (int j = 0; j < 4; ++j)
                    acc[i][j] = __builtin_amdgcn_mfma_f32_16x16x32_bf16(
                        a_frag[i], b_frag[j], acc[i][j], 0, 0, 0);
        }
        __syncthreads();
    }

    int rg = (lane >> 4) * 4;
    #pragma unroll
    for (int i = 0; i < 4; ++i) {
        #pragma unroll
        for (int j = 0; j < 4; ++j) {
            int n = col0 + wn + j * 16 + fr;
            float bv = bias ? bias[n] : 0.0f;
            #pragma unroll
            for (int r = 0; r < 4; ++r) {
                int m = row0 + wm + i * 16 + rg + r;
                Cb[(size_t)m * DIM + n] = f2bf(acc[i][j][r] + bv);
            }
        }
    }
}

__global__ __launch_bounds__(256, 4) void gemm_kernel(const unsigned short* __restrict__ A,
                                                      const unsigned short* __restrict__ BT,
                                                      unsigned short* __restrict__ Cb,
                                                      const float* __restrict__ bias) {
    int bx, by;
    xcd_pair(blockIdx.x, bx, by);
    gemm_body(bx, by, A, BT, Cb, bias);
}

// ---------------- combo2: projection GEMM + CSR fill (independent outputs) ----------------

__global__ __launch_bounds__(256, 4) void combo2(const unsigned short* __restrict__ A,
                                                 const unsigned short* __restrict__ BT,
                                                 unsigned short* __restrict__ Cb,
                                                 const float* __restrict__ bias,
                                                 const int* __restrict__ src,
                                                 const int* __restrict__ dst,
                                                 int* __restrict__ cursor,
                                                 int* __restrict__ csr) {
    int b = blockIdx.x;
    if (b < GEMM_BLOCKS) {
        int bx, by;
        xcd_pair(b, bx, by);
        gemm_body(bx, by, A, BT, Cb, bias);
    } else {
        int i = (b - GEMM_BLOCKS) * 256 + threadIdx.x;
        if (i < NEDGES) {
            int pos = atomicAdd(&cursor[dst[i]], 1);
            csr[pos] = src[i];
        }
    }
}

// ---------------- edge softmax + aggregation with IN-WAVE el/er ----------------
// One wave per dst node; 32 lanes per edge, 2 edges per iteration (round-0
// proven gather structure). NEW: el[u], el_v, er_v are computed IN-WAVE from
// the h rows the wave already reads, instead of a separate eler pass:
//   - lane holds 8 dims of one head (4-lane group = full 32-dim head)
//   - per-lane 8-dim dot with al/ar, then shfl_xor(1) + shfl_xor(2) reduce
//     over the 4-lane head group.
// Shfl safety (r1/r2 lesson): the 4-lane group is 4-aligned so it never
// crosses the halfe boundary (halfe = lane>>5 uniform within group), and
// beg/end are wave-uniform -> all 4 lanes always co-active at the shfl.
// Kills the 2 eler dispatches + el/er buffers + the per-edge el gather
// (~16 MB of FETCH); adds ~12 VALU/edge, which hides under gather latency
// (VALU-work 23.6us -> ~36us, still < 50us memory-bound time).

__global__ __launch_bounds__(256) void agg_kernel(const unsigned short* __restrict__ Hb,
                                                  const float* __restrict__ al,
                                                  const float* __restrict__ ar,
                                                  const int* __restrict__ rowptr,
                                                  const int* __restrict__ csr,
                                                  const float* __restrict__ bias,
                                                  float* __restrict__ outf,
                                                  unsigned short* __restrict__ outb) {
    int wave = threadIdx.x >> 6;
    int lane = threadIdx.x & 63;
    int v = blockIdx.x * 4 + wave;
    if (v >= NNODES) return;
    int sub = lane & 31;     // lane within half-wave
    int halfe = lane >> 5;   // which edge of the pair this half handles
    int c0 = sub * 8;        // dim offset (8 dims/lane)

    // attention vectors for this lane's 8 dims
    float4 a0 = *(const float4*)(al + c0);
    float4 a1 = *(const float4*)(al + c0 + 4);
    float4 g0 = *(const float4*)(ar + c0);
    float4 g1 = *(const float4*)(ar + c0 + 4);

    // self row: both halves load (same cache lines) and derive el_v, er_v
    bf16x8 hv = *(const bf16x8*)(Hb + (size_t)v * DIM + c0);
    float hvf[8];
    #pragma unroll
    for (int d = 0; d < 8; ++d) hvf[d] = bf2f_s(hv[d]);
    float dl = hvf[0] * a0.x + hvf[1] * a0.y + hvf[2] * a0.z + hvf[3] * a0.w
             + hvf[4] * a1.x + hvf[5] * a1.y + hvf[6] * a1.z + hvf[7] * a1.w;
    float dr = hvf[0] * g0.x + hvf[1] * g0.y + hvf[2] * g0.z + hvf[3] * g0.w
             + hvf[4] * g1.x + hvf[5] * g1.y + hvf[6] * g1.z + hvf[7] * g1.w;
    dl += __shfl_xor(dl, 1, 64); dl += __shfl_xor(dl, 2, 64);
    dr += __shfl_xor(dr, 1, 64); dr += __shfl_xor(dr, 2, 64);
    float el_v = dl, er_v = dr;

    int beg = rowptr[v], end = rowptr[v + 1];

    float z = 0.0f;
    float acc[8] = {0.f, 0.f, 0.f, 0.f, 0.f, 0.f, 0.f, 0.f};

    // self loop on half 0 only
    if (halfe == 0) {
        float ws = __expf(leaky(el_v + er_v));
        z = ws;
        #pragma unroll
        for (int d = 0; d < 8; ++d) acc[d] = ws * hvf[d];
    }

    #pragma unroll 4
    for (int i = beg + halfe; i < end; i += 2) {
        int u = csr[i];
        bf16x8 h = *(const bf16x8*)(Hb + (size_t)u * DIM + c0);
        float hf[8];
        #pragma unroll
        for (int d = 0; d < 8; ++d) hf[d] = bf2f_s(h[d]);
        float du = hf[0] * a0.x + hf[1] * a0.y + hf[2] * a0.z + hf[3] * a0.w
                 + hf[4] * a1.x + hf[5] * a1.y + hf[6] * a1.z + hf[7] * a1.w;
        du += __shfl_xor(du, 1, 64);
        du += __shfl_xor(du, 2, 64);
        float e = leaky(du + er_v);
        float wi = __expf(e);
        z += wi;
        #pragma unroll
        for (int d = 0; d < 8; ++d) acc[d] += wi * hf[d];
    }

    // cross-half reduction: both halves end with full totals
    z += __shfl_xor(z, 32, 64);
    #pragma unroll
    for (int d = 0; d < 8; ++d) acc[d] += __shfl_xor(acc[d], 32, 64);

    float inv = 1.0f / z;
    // each half stores 4 of the lane's 8 dims: half0 -> dims[0..3], half1 -> dims[4..7]
    int o0 = c0 + halfe * 4;
    float4 b = *(const float4*)(bias + o0);
    float r0 = leaky(acc[halfe * 4 + 0] * inv + b.x);
    float r1 = leaky(acc[halfe * 4 + 1] * inv + b.y);
    float r2 = leaky(acc[halfe * 4 + 2] * inv + b.z);
    float r3 = leaky(acc[halfe * 4 + 3] * inv + b.w);
    if (outf) {
        float4 o = { r0, r1, r2, r3 };
        *(float4*)(outf + (size_t)v * DIM + o0) = o;
    } else {
        u16x4 o;
        o.x = f2bf(r0); o.y = f2bf(r1); o.z = f2bf(r2); o.w = f2bf(r3);
        *(u16x4*)(outb + (size_t)v * DIM + o0) = o;
    }
}

// ---------------- launch ----------------

static inline size_t align256(size_t x) { return (x + 255) & ~(size_t)255; }

extern "C" void kernel_launch(void* const* d_in, const int* in_sizes, int n_in,
                              void* d_out, int out_size, void* d_ws, size_t ws_size,
                              hipStream_t stream) {
    const float* feats  = (const float*)d_in[0];
    const int*   src    = (const int*)d_in[1];
    const int*   dst    = (const int*)d_in[2];
    const float* proj_W = (const float*)d_in[3];
    const float* proj_b = (const float*)d_in[4];
    const float* W1     = (const float*)d_in[5];
    const float* al1    = (const float*)d_in[6];
    const float* ar1    = (const float*)d_in[7];
    const float* b1     = (const float*)d_in[8];
    const float* W2     = (const float*)d_in[9];
    const float* al2    = (const float*)d_in[10];
    const float* ar2    = (const float*)d_in[11];
    const float* b2     = (const float*)d_in[12];
    float* out = (float*)d_out;

    uint8_t* w = (uint8_t*)d_ws;
    unsigned short* Abf = (unsigned short*)w; w += align256((size_t)MPAD * DIM * 2);
    unsigned short* Bbf = (unsigned short*)w; w += align256((size_t)MPAD * DIM * 2);
    unsigned short* Hb  = (unsigned short*)w; w += align256((size_t)MPAD * DIM * 2);
    unsigned short* WT  = (unsigned short*)w; w += align256((size_t)3 * DIM * DIM * 2);
    int* deg    = (int*)w;            w += align256((size_t)NNODES * 4);
    int* rowptr = (int*)w;            w += align256((size_t)(NNODES + 1) * 4);
    int* cursor = (int*)w;            w += align256((size_t)NNODES * 4);
    int* csr    = (int*)w;            w += align256((size_t)NEDGES * 4);
    int* bsum   = (int*)w;            w += align256((size_t)SCAN_BLOCKS * 4);
    int* boff   = (int*)w;            w += align256((size_t)SCAN_BLOCKS * 4);

    unsigned short* WT0 = WT;
    unsigned short* WT1 = WT + (size_t)DIM * DIM;
    unsigned short* WT2 = WT + (size_t)2 * DIM * DIM;

    const int node_wave_blocks = (NNODES + 3) / 4;  // one wave per node

    hipMemsetAsync(deg, 0, (size_t)NNODES * 4, stream);

    // count + feats->bf16 + weight transpose, one dispatch
    combo1<<<COUNT_BLOCKS + CVT_BLOCKS + TR_BLOCKS, 256, 0, stream>>>(
        dst, deg, feats, Abf, proj_W, W1, W2, WT);

    scanA_kernel<<<SCAN_BLOCKS, 256, 0, stream>>>(deg, bsum);
    scanB_kernel<<<1, 256, 0, stream>>>(bsum, boff, rowptr);
    scanC_kernel<<<SCAN_BLOCKS, 256, 0, stream>>>(deg, boff, rowptr, cursor);

    // projection gemm + CSR fill, one dispatch
    combo2<<<GEMM_BLOCKS + COUNT_BLOCKS, 256, 0, stream>>>(
        Abf, WT0, Bbf, proj_b, src, dst, cursor, csr);

    // layer 1: Hb = Bbf @ W1 ; agg (in-wave el/er) -> Abf (bf16)
    gemm_kernel<<<GEMM_BLOCKS, 256, 0, stream>>>(Bbf, WT1, Hb, nullptr);
    agg_kernel<<<node_wave_blocks, 256, 0, stream>>>(Hb, al1, ar1, rowptr, csr, b1,
                                                     nullptr, Abf);

    // layer 2: Hb = Abf @ W2 ; agg (in-wave el/er) -> out (fp32)
    gemm_kernel<<<GEMM_BLOCKS, 256, 0, stream>>>(Abf, WT2, Hb, nullptr);
    agg_kernel<<<node_wave_blocks, 256, 0, stream>>>(Hb, al2, ar2, rowptr, csr, b2,
                                                     out, nullptr);
}

// Round 10
// 306.717 us; speedup vs baseline: 1.1721x; 1.0133x over previous
//
#include <hip/hip_runtime.h>
#include <stdint.h>
#include <stddef.h>

#define NNODES 50000
#define NEDGES 500000
#define DIM 256
#define NHEAD 8
#define HDIM 32
#define MPAD 50048   /* 391 * 128 */
#define NEGS 0.2f
#define SCAN_BLOCKS 196    /* ceil(50000/256) */
#define COUNT_BLOCKS 1954  /* ceil(500000/256) */
#define CVT_BLOCKS 12500   /* 50000*256/1024 */
#define TR_BLOCKS 192      /* 8*8*3 */
#define GEMM_BLOCKS 782    /* 391*2 */

typedef __attribute__((ext_vector_type(8))) short bf16x8;
typedef __attribute__((ext_vector_type(4))) float f32x4;
typedef __attribute__((ext_vector_type(4))) unsigned short u16x4;

__device__ __forceinline__ unsigned short f2bf(float f) {
    uint32_t u = __builtin_bit_cast(uint32_t, f);
    uint32_t r = (u + 0x7FFFu + ((u >> 16) & 1u)) >> 16;
    return (unsigned short)r;
}

__device__ __forceinline__ float bf2f(unsigned short u) {
    return __builtin_bit_cast(float, (uint32_t)u << 16);
}

__device__ __forceinline__ float bf2f_s(short u) {
    return __builtin_bit_cast(float, (uint32_t)(unsigned short)u << 16);
}

__device__ __forceinline__ float leaky(float x) {
    return x > 0.0f ? x : NEGS * x;
}

__device__ __forceinline__ void gld_lds16(const unsigned short* g, unsigned short* l) {
    __builtin_amdgcn_global_load_lds(
        (const __attribute__((address_space(1))) void*)g,
        (__attribute__((address_space(3))) void*)l,
        16, 0, 0);
}

// Bijective XCD pair-swizzle for 782 blocks over 8 XCDs (q=97, r=6).
// Makes the two blocks sharing an A-panel (same bx) run on the SAME XCD
// back-to-back -> A read ~once from HBM (r6/r7 FETCH=15MB confirms). Perf-only.
__device__ __forceinline__ void xcd_pair(int orig, int& bx, int& by) {
    int x = orig & 7, g = orig >> 3;
    int v = (x < 6 ? x * 98 : 588 + (x - 6) * 97) + g;
    bx = v >> 1;
    by = v & 1;
}

// ---------------- CSR scan kernels (baseline, unchanged) ----------------

__global__ __launch_bounds__(256) void scanA_kernel(const int* __restrict__ deg,
                                                    int* __restrict__ bsum) {
    __shared__ int ws[4];
    int t = threadIdx.x;
    int idx = blockIdx.x * 256 + t;
    int v = (idx < NNODES) ? deg[idx] : 0;
    int x = v;
    #pragma unroll
    for (int off = 1; off < 64; off <<= 1) x += __shfl_xor(x, off, 64);
    if ((t & 63) == 0) ws[t >> 6] = x;
    __syncthreads();
    if (t == 0) bsum[blockIdx.x] = ws[0] + ws[1] + ws[2] + ws[3];
}

__global__ __launch_bounds__(256) void scanB_kernel(const int* __restrict__ bsum,
                                                    int* __restrict__ boff,
                                                    int* __restrict__ rowptr) {
    __shared__ int s[256];
    int t = threadIdx.x;
    int v = (t < SCAN_BLOCKS) ? bsum[t] : 0;
    s[t] = v;
    __syncthreads();
    #pragma unroll
    for (int off = 1; off < 256; off <<= 1) {
        int y = (t >= off) ? s[t - off] : 0;
        __syncthreads();
        s[t] += y;
        __syncthreads();
    }
    if (t < SCAN_BLOCKS) boff[t] = s[t] - v;  // exclusive
    if (t == 0) rowptr[NNODES] = NEDGES;
}

__global__ __launch_bounds__(256) void scanC_kernel(const int* __restrict__ deg,
                                                    const int* __restrict__ boff,
                                                    int* __restrict__ rowptr,
                                                    int* __restrict__ cursor) {
    __shared__ int ws[4];
    int t = threadIdx.x;
    int lane = t & 63, wv = t >> 6;
    int idx = blockIdx.x * 256 + t;
    int v = (idx < NNODES) ? deg[idx] : 0;
    int x = v;
    #pragma unroll
    for (int off = 1; off < 64; off <<= 1) {
        int y = __shfl_up(x, off, 64);
        if (lane >= off) x += y;
    }
    if (lane == 63) ws[wv] = x;
    __syncthreads();
    int wadd = 0;
    #pragma unroll
    for (int k = 0; k < 4; ++k) if (k < wv) wadd += ws[k];
    int excl = x - v + wadd + boff[blockIdx.x];
    if (idx < NNODES) { rowptr[idx] = excl; cursor[idx] = excl; }
}

// ---------------- combo1: count (atomic) + feats cvt (BW) + weight transpose ----------------

__global__ __launch_bounds__(256) void combo1(const int* __restrict__ dst,
                                              int* __restrict__ deg,
                                              const float* __restrict__ feats,
                                              unsigned short* __restrict__ Abf,
                                              const float* __restrict__ W0,
                                              const float* __restrict__ W1,
                                              const float* __restrict__ W2,
                                              unsigned short* __restrict__ WT) {
    __shared__ float tile[32][33];
    int b = blockIdx.x;
    if (b < COUNT_BLOCKS) {
        int i = b * 256 + threadIdx.x;
        if (i < NEDGES) atomicAdd(&deg[dst[i]], 1);
    } else if (b < COUNT_BLOCKS + CVT_BLOCKS) {
        int i = ((b - COUNT_BLOCKS) * 256 + threadIdx.x) * 4;
        const float4 v = *(const float4*)(feats + i);
        u16x4 o;
        o.x = f2bf(v.x); o.y = f2bf(v.y); o.z = f2bf(v.z); o.w = f2bf(v.w);
        *(u16x4*)(Abf + i) = o;
    } else {
        int t = b - COUNT_BLOCKS - CVT_BLOCKS;  // 0..191
        int bz = t >> 6;
        int bx = t & 7;          // n tile
        int by = (t >> 3) & 7;   // k tile
        const float* W = (bz == 0) ? W0 : (bz == 1) ? W1 : W2;
        unsigned short* T = WT + (size_t)bz * DIM * DIM;
        int tx = threadIdx.x & 31, ty = threadIdx.x >> 5;  // 32 x 8
        #pragma unroll
        for (int j = 0; j < 4; ++j)
            tile[ty + j * 8][tx] = W[(by * 32 + ty + j * 8) * DIM + bx * 32 + tx];
        __syncthreads();
        #pragma unroll
        for (int j = 0; j < 4; ++j)
            T[(bx * 32 + ty + j * 8) * DIM + by * 32 + tx] = f2bf(tile[tx][ty + j * 8]);
    }
}

// ---------------- GEMM body: BK=32 DOUBLE-BUFFERED staging, 32 KB LDS ----------------
// Cb[M][256](bf16) = A[M][256](bf16) @ W (+bias), 128x128 tile.
// vs r7/r8 (stage -> sync -> compute -> sync, stage latency fully exposed):
// the next K=32 slab's 4 gld_lds are issued BEFORE computing the current
// buffer, so the HBM latency overlaps the 16 MFMA + 8 ds_read. One barrier
// per K-step (same count as r7). This is r6's dbuf idea WITHOUT r6's
// confound (B stays LDS-staged; B-from-global was the r6 regression).
// Buffer ledger: STAGE@kt writes buf^1 (last read by compute@kt-1, WAR
// separated by the kt-1 barrier); compute@kt reads buf staged @kt-1 (RAW
// drained by that barrier's implicit vmcnt(0)). Final iter: no barrier needed.
// __launch_bounds__(256,4): keeps regs <= 128/wave -> 4 blocks/CU (r8 win).

__device__ __forceinline__ void gemm_body(int bx, int by,
        const unsigned short* __restrict__ A, const unsigned short* __restrict__ BT,
        unsigned short* __restrict__ Cb, const float* __restrict__ bias) {
    __shared__ __align__(16) unsigned short As[2][128][32];  // 16 KB
    __shared__ __align__(16) unsigned short Bs[2][128][32];  // 16 KB
    int tid = threadIdx.x;
    int wave = tid >> 6, lane = tid & 63;
    int row0 = bx * 128;
    int col0 = by * 128;
    int wm = (wave >> 1) * 64;
    int wn = (wave & 1) * 64;

    f32x4 acc[4][4] = {};

    int fr = lane & 15;
    int kg = (lane >> 4) * 8;

    // stage one K=32 slab (128 rows x 32 k = 8 KB each of A,B):
    // 512 x 16B chunks -> 2 per thread; row = idx>>2, q = idx&3
    #define STAGE32(buf, kt)                                                      \
        do {                                                                      \
            _Pragma("unroll")                                                     \
            for (int r_ = 0; r_ < 2; ++r_) {                                      \
                int idx_ = r_ * 256 + tid;                                        \
                int row_ = idx_ >> 2;                                             \
                int q_ = idx_ & 3;                                                \
                gld_lds16(A + (size_t)(row0 + row_) * DIM + (kt) * 32 + q_ * 8,   \
                          &As[buf][0][0] + idx_ * 8);                             \
                gld_lds16(BT + (size_t)(col0 + row_) * DIM + (kt) * 32 + q_ * 8,  \
                          &Bs[buf][0][0] + idx_ * 8);                             \
            }                                                                     \
        } while (0)

    STAGE32(0, 0);
    __syncthreads();

    int cur = 0;
    #pragma unroll
    for (int kt = 0; kt < 8; ++kt) {
        if (kt < 7) STAGE32(cur ^ 1, kt + 1);
        bf16x8 a_frag[4], b_frag[4];
        #pragma unroll
        for (int i = 0; i < 4; ++i) {
            a_frag[i] = *(const bf16x8*)(&As[cur][wm + i * 16 + fr][kg]);
            b_frag[i] = *(const bf16x8*)(&Bs[cur][wn + i * 16 + fr][kg]);
        }
        #pragma unroll
        for (int i = 0; i < 4; ++i)
            #pragma unroll
            for (int j = 0; j < 4; ++j)
                acc[i][j] = __builtin_amdgcn_mfma_f32_16x16x32_bf16(
                    a_frag[i], b_frag[j], acc[i][j], 0, 0, 0);
        if (kt < 7) { __syncthreads(); cur ^= 1; }
    }
    #undef STAGE32

    int rg = (lane >> 4) * 4;
    #pragma unroll
    for (int i = 0; i < 4; ++i) {
        #pragma unroll
        for (int j = 0; j < 4; ++j) {
            int n = col0 + wn + j * 16 + fr;
            float bv = bias ? bias[n] : 0.0f;
            #pragma unroll
            for (int r = 0; r < 4; ++r) {
                int m = row0 + wm + i * 16 + rg + r;
                Cb[(size_t)m * DIM + n] = f2bf(acc[i][j][r] + bv);
            }
        }
    }
}

__global__ __launch_bounds__(256, 4) void gemm_kernel(const unsigned short* __restrict__ A,
                                                      const unsigned short* __restrict__ BT,
                                                      unsigned short* __restrict__ Cb,
                                                      const float* __restrict__ bias) {
    int bx, by;
    xcd_pair(blockIdx.x, bx, by);
    gemm_body(bx, by, A, BT, Cb, bias);
}

// ---------------- combo2: projection GEMM + CSR fill (independent outputs) ----------------

__global__ __launch_bounds__(256, 4) void combo2(const unsigned short* __restrict__ A,
                                                 const unsigned short* __restrict__ BT,
                                                 unsigned short* __restrict__ Cb,
                                                 const float* __restrict__ bias,
                                                 const int* __restrict__ src,
                                                 const int* __restrict__ dst,
                                                 int* __restrict__ cursor,
                                                 int* __restrict__ csr) {
    int b = blockIdx.x;
    if (b < GEMM_BLOCKS) {
        int bx, by;
        xcd_pair(b, bx, by);
        gemm_body(bx, by, A, BT, Cb, bias);
    } else {
        int i = (b - GEMM_BLOCKS) * 256 + threadIdx.x;
        if (i < NEDGES) {
            int pos = atomicAdd(&cursor[dst[i]], 1);
            csr[pos] = src[i];
        }
    }
}

// ---------------- edge softmax + aggregation with IN-WAVE el/er (r9, proven) ----------------
// One wave per dst node; 32 lanes per edge, 2 edges per iteration. el[u],
// el_v, er_v computed in-wave from the h rows the wave already reads
// (8-dim dot + shfl_xor{1,2} over the 4-lane head group; group never crosses
// the halfe boundary and beg/end are wave-uniform -> no inactive-lane shfl).
// r9: killed eler dispatches + 24 MB FETCH; agg 50.2 -> 53.5 but net -11 us.

__global__ __launch_bounds__(256) void agg_kernel(const unsigned short* __restrict__ Hb,
                                                  const float* __restrict__ al,
                                                  const float* __restrict__ ar,
                                                  const int* __restrict__ rowptr,
                                                  const int* __restrict__ csr,
                                                  const float* __restrict__ bias,
                                                  float* __restrict__ outf,
                                                  unsigned short* __restrict__ outb) {
    int wave = threadIdx.x >> 6;
    int lane = threadIdx.x & 63;
    int v = blockIdx.x * 4 + wave;
    if (v >= NNODES) return;
    int sub = lane & 31;     // lane within half-wave
    int halfe = lane >> 5;   // which edge of the pair this half handles
    int c0 = sub * 8;        // dim offset (8 dims/lane)

    // attention vectors for this lane's 8 dims
    float4 a0 = *(const float4*)(al + c0);
    float4 a1 = *(const float4*)(al + c0 + 4);
    float4 g0 = *(const float4*)(ar + c0);
    float4 g1 = *(const float4*)(ar + c0 + 4);

    // self row: both halves load (same cache lines) and derive el_v, er_v
    bf16x8 hv = *(const bf16x8*)(Hb + (size_t)v * DIM + c0);
    float hvf[8];
    #pragma unroll
    for (int d = 0; d < 8; ++d) hvf[d] = bf2f_s(hv[d]);
    float dl = hvf[0] * a0.x + hvf[1] * a0.y + hvf[2] * a0.z + hvf[3] * a0.w
             + hvf[4] * a1.x + hvf[5] * a1.y + hvf[6] * a1.z + hvf[7] * a1.w;
    float dr = hvf[0] * g0.x + hvf[1] * g0.y + hvf[2] * g0.z + hvf[3] * g0.w
             + hvf[4] * g1.x + hvf[5] * g1.y + hvf[6] * g1.z + hvf[7] * g1.w;
    dl += __shfl_xor(dl, 1, 64); dl += __shfl_xor(dl, 2, 64);
    dr += __shfl_xor(dr, 1, 64); dr += __shfl_xor(dr, 2, 64);
    float el_v = dl, er_v = dr;

    int beg = rowptr[v], end = rowptr[v + 1];

    float z = 0.0f;
    float acc[8] = {0.f, 0.f, 0.f, 0.f, 0.f, 0.f, 0.f, 0.f};

    // self loop on half 0 only
    if (halfe == 0) {
        float ws = __expf(leaky(el_v + er_v));
        z = ws;
        #pragma unroll
        for (int d = 0; d < 8; ++d) acc[d] = ws * hvf[d];
    }

    #pragma unroll 4
    for (int i = beg + halfe; i < end; i += 2) {
        int u = csr[i];
        bf16x8 h = *(const bf16x8*)(Hb + (size_t)u * DIM + c0);
        float hf[8];
        #pragma unroll
        for (int d = 0; d < 8; ++d) hf[d] = bf2f_s(h[d]);
        float du = hf[0] * a0.x + hf[1] * a0.y + hf[2] * a0.z + hf[3] * a0.w
                 + hf[4] * a1.x + hf[5] * a1.y + hf[6] * a1.z + hf[7] * a1.w;
        du += __shfl_xor(du, 1, 64);
        du += __shfl_xor(du, 2, 64);
        float e = leaky(du + er_v);
        float wi = __expf(e);
        z += wi;
        #pragma unroll
        for (int d = 0; d < 8; ++d) acc[d] += wi * hf[d];
    }

    // cross-half reduction: both halves end with full totals
    z += __shfl_xor(z, 32, 64);
    #pragma unroll
    for (int d = 0; d < 8; ++d) acc[d] += __shfl_xor(acc[d], 32, 64);

    float inv = 1.0f / z;
    // each half stores 4 of the lane's 8 dims: half0 -> dims[0..3], half1 -> dims[4..7]
    int o0 = c0 + halfe * 4;
    float4 b = *(const float4*)(bias + o0);
    float r0 = leaky(acc[halfe * 4 + 0] * inv + b.x);
    float r1 = leaky(acc[halfe * 4 + 1] * inv + b.y);
    float r2 = leaky(acc[halfe * 4 + 2] * inv + b.z);
    float r3 = leaky(acc[halfe * 4 + 3] * inv + b.w);
    if (outf) {
        float4 o = { r0, r1, r2, r3 };
        *(float4*)(outf + (size_t)v * DIM + o0) = o;
    } else {
        u16x4 o;
        o.x = f2bf(r0); o.y = f2bf(r1); o.z = f2bf(r2); o.w = f2bf(r3);
        *(u16x4*)(outb + (size_t)v * DIM + o0) = o;
    }
}

// ---------------- launch ----------------

static inline size_t align256(size_t x) { return (x + 255) & ~(size_t)255; }

extern "C" void kernel_launch(void* const* d_in, const int* in_sizes, int n_in,
                              void* d_out, int out_size, void* d_ws, size_t ws_size,
                              hipStream_t stream) {
    const float* feats  = (const float*)d_in[0];
    const int*   src    = (const int*)d_in[1];
    const int*   dst    = (const int*)d_in[2];
    const float* proj_W = (const float*)d_in[3];
    const float* proj_b = (const float*)d_in[4];
    const float* W1     = (const float*)d_in[5];
    const float* al1    = (const float*)d_in[6];
    const float* ar1    = (const float*)d_in[7];
    const float* b1     = (const float*)d_in[8];
    const float* W2     = (const float*)d_in[9];
    const float* al2    = (const float*)d_in[10];
    const float* ar2    = (const float*)d_in[11];
    const float* b2     = (const float*)d_in[12];
    float* out = (float*)d_out;

    uint8_t* w = (uint8_t*)d_ws;
    unsigned short* Abf = (unsigned short*)w; w += align256((size_t)MPAD * DIM * 2);
    unsigned short* Bbf = (unsigned short*)w; w += align256((size_t)MPAD * DIM * 2);
    unsigned short* Hb  = (unsigned short*)w; w += align256((size_t)MPAD * DIM * 2);
    unsigned short* WT  = (unsigned short*)w; w += align256((size_t)3 * DIM * DIM * 2);
    int* deg    = (int*)w;            w += align256((size_t)NNODES * 4);
    int* rowptr = (int*)w;            w += align256((size_t)(NNODES + 1) * 4);
    int* cursor = (int*)w;            w += align256((size_t)NNODES * 4);
    int* csr    = (int*)w;            w += align256((size_t)NEDGES * 4);
    int* bsum   = (int*)w;            w += align256((size_t)SCAN_BLOCKS * 4);
    int* boff   = (int*)w;            w += align256((size_t)SCAN_BLOCKS * 4);

    unsigned short* WT0 = WT;
    unsigned short* WT1 = WT + (size_t)DIM * DIM;
    unsigned short* WT2 = WT + (size_t)2 * DIM * DIM;

    const int node_wave_blocks = (NNODES + 3) / 4;  // one wave per node

    hipMemsetAsync(deg, 0, (size_t)NNODES * 4, stream);

    // count + feats->bf16 + weight transpose, one dispatch
    combo1<<<COUNT_BLOCKS + CVT_BLOCKS + TR_BLOCKS, 256, 0, stream>>>(
        dst, deg, feats, Abf, proj_W, W1, W2, WT);

    scanA_kernel<<<SCAN_BLOCKS, 256, 0, stream>>>(deg, bsum);
    scanB_kernel<<<1, 256, 0, stream>>>(bsum, boff, rowptr);
    scanC_kernel<<<SCAN_BLOCKS, 256, 0, stream>>>(deg, boff, rowptr, cursor);

    // projection gemm + CSR fill, one dispatch
    combo2<<<GEMM_BLOCKS + COUNT_BLOCKS, 256, 0, stream>>>(
        Abf, WT0, Bbf, proj_b, src, dst, cursor, csr);

    // layer 1: Hb = Bbf @ W1 ; agg (in-wave el/er) -> Abf (bf16)
    gemm_kernel<<<GEMM_BLOCKS, 256, 0, stream>>>(Bbf, WT1, Hb, nullptr);
    agg_kernel<<<node_wave_blocks, 256, 0, stream>>>(Hb, al1, ar1, rowptr, csr, b1,
                                                     nullptr, Abf);

    // layer 2: Hb = Abf @ W2 ; agg (in-wave el/er) -> out (fp32)
    gemm_kernel<<<GEMM_BLOCKS, 256, 0, stream>>>(Abf, WT2, Hb, nullptr);
    agg_kernel<<<node_wave_blocks, 256, 0, stream>>>(Hb, al2, ar2, rowptr, csr, b2,
                                                     out, nullptr);
}

// Round 11
// 305.272 us; speedup vs baseline: 1.1777x; 1.0047x over previous
//
#include <hip/hip_runtime.h>
#include <stdint.h>
#include <stddef.h>

#define NNODES 50000
#define NEDGES 500000
#define DIM 256
#define NHEAD 8
#define HDIM 32
#define MPAD 50048   /* 391 * 128 */
#define NEGS 0.2f
#define SCAN_BLOCKS 196    /* ceil(50000/256) */
#define COUNT_BLOCKS 1954  /* ceil(500000/256) */
#define CVT_BLOCKS 12500   /* 50000*256/1024 */
#define TR_BLOCKS 192      /* 8*8*3 */
#define GEMM_BLOCKS 782    /* 391*2 */

typedef __attribute__((ext_vector_type(8))) short bf16x8;
typedef __attribute__((ext_vector_type(4))) float f32x4;
typedef __attribute__((ext_vector_type(2))) float f32x2;
typedef __attribute__((ext_vector_type(4))) unsigned short u16x4;

__device__ __forceinline__ unsigned short f2bf(float f) {
    uint32_t u = __builtin_bit_cast(uint32_t, f);
    uint32_t r = (u + 0x7FFFu + ((u >> 16) & 1u)) >> 16;
    return (unsigned short)r;
}

__device__ __forceinline__ float bf2f(unsigned short u) {
    return __builtin_bit_cast(float, (uint32_t)u << 16);
}

__device__ __forceinline__ float bf2f_s(short u) {
    return __builtin_bit_cast(float, (uint32_t)(unsigned short)u << 16);
}

// two bf16 in a u32 -> f32 pair (elem0 = low half, elem1 = high half)
__device__ __forceinline__ f32x2 bfpair(uint32_t w) {
    f32x2 r;
    r.x = __builtin_bit_cast(float, w << 16);
    r.y = __builtin_bit_cast(float, w & 0xffff0000u);
    return r;
}

__device__ __forceinline__ float leaky(float x) {
    return x > 0.0f ? x : NEGS * x;
}

__device__ __forceinline__ void gld_lds16(const unsigned short* g, unsigned short* l) {
    __builtin_amdgcn_global_load_lds(
        (const __attribute__((address_space(1))) void*)g,
        (__attribute__((address_space(3))) void*)l,
        16, 0, 0);
}

// Bijective XCD pair-swizzle for 782 blocks over 8 XCDs (q=97, r=6).
// Makes the two blocks sharing an A-panel (same bx) run on the SAME XCD
// back-to-back -> A read ~once from HBM (r6/r7 FETCH=15MB confirms). Perf-only.
__device__ __forceinline__ void xcd_pair(int orig, int& bx, int& by) {
    int x = orig & 7, g = orig >> 3;
    int v = (x < 6 ? x * 98 : 588 + (x - 6) * 97) + g;
    bx = v >> 1;
    by = v & 1;
}

// ---------------- CSR scan kernels (baseline, unchanged) ----------------

__global__ __launch_bounds__(256) void scanA_kernel(const int* __restrict__ deg,
                                                    int* __restrict__ bsum) {
    __shared__ int ws[4];
    int t = threadIdx.x;
    int idx = blockIdx.x * 256 + t;
    int v = (idx < NNODES) ? deg[idx] : 0;
    int x = v;
    #pragma unroll
    for (int off = 1; off < 64; off <<= 1) x += __shfl_xor(x, off, 64);
    if ((t & 63) == 0) ws[t >> 6] = x;
    __syncthreads();
    if (t == 0) bsum[blockIdx.x] = ws[0] + ws[1] + ws[2] + ws[3];
}

__global__ __launch_bounds__(256) void scanB_kernel(const int* __restrict__ bsum,
                                                    int* __restrict__ boff,
                                                    int* __restrict__ rowptr) {
    __shared__ int s[256];
    int t = threadIdx.x;
    int v = (t < SCAN_BLOCKS) ? bsum[t] : 0;
    s[t] = v;
    __syncthreads();
    #pragma unroll
    for (int off = 1; off < 256; off <<= 1) {
        int y = (t >= off) ? s[t - off] : 0;
        __syncthreads();
        s[t] += y;
        __syncthreads();
    }
    if (t < SCAN_BLOCKS) boff[t] = s[t] - v;  // exclusive
    if (t == 0) rowptr[NNODES] = NEDGES;
}

__global__ __launch_bounds__(256) void scanC_kernel(const int* __restrict__ deg,
                                                    const int* __restrict__ boff,
                                                    int* __restrict__ rowptr,
                                                    int* __restrict__ cursor) {
    __shared__ int ws[4];
    int t = threadIdx.x;
    int lane = t & 63, wv = t >> 6;
    int idx = blockIdx.x * 256 + t;
    int v = (idx < NNODES) ? deg[idx] : 0;
    int x = v;
    #pragma unroll
    for (int off = 1; off < 64; off <<= 1) {
        int y = __shfl_up(x, off, 64);
        if (lane >= off) x += y;
    }
    if (lane == 63) ws[wv] = x;
    __syncthreads();
    int wadd = 0;
    #pragma unroll
    for (int k = 0; k < 4; ++k) if (k < wv) wadd += ws[k];
    int excl = x - v + wadd + boff[blockIdx.x];
    if (idx < NNODES) { rowptr[idx] = excl; cursor[idx] = excl; }
}

// ---------------- combo1: count (atomic) + feats cvt (BW) + weight transpose ----------------

__global__ __launch_bounds__(256) void combo1(const int* __restrict__ dst,
                                              int* __restrict__ deg,
                                              const float* __restrict__ feats,
                                              unsigned short* __restrict__ Abf,
                                              const float* __restrict__ W0,
                                              const float* __restrict__ W1,
                                              const float* __restrict__ W2,
                                              unsigned short* __restrict__ WT) {
    __shared__ float tile[32][33];
    int b = blockIdx.x;
    if (b < COUNT_BLOCKS) {
        int i = b * 256 + threadIdx.x;
        if (i < NEDGES) atomicAdd(&deg[dst[i]], 1);
    } else if (b < COUNT_BLOCKS + CVT_BLOCKS) {
        int i = ((b - COUNT_BLOCKS) * 256 + threadIdx.x) * 4;
        const float4 v = *(const float4*)(feats + i);
        u16x4 o;
        o.x = f2bf(v.x); o.y = f2bf(v.y); o.z = f2bf(v.z); o.w = f2bf(v.w);
        *(u16x4*)(Abf + i) = o;
    } else {
        int t = b - COUNT_BLOCKS - CVT_BLOCKS;  // 0..191
        int bz = t >> 6;
        int bx = t & 7;          // n tile
        int by = (t >> 3) & 7;   // k tile
        const float* W = (bz == 0) ? W0 : (bz == 1) ? W1 : W2;
        unsigned short* T = WT + (size_t)bz * DIM * DIM;
        int tx = threadIdx.x & 31, ty = threadIdx.x >> 5;  // 32 x 8
        #pragma unroll
        for (int j = 0; j < 4; ++j)
            tile[ty + j * 8][tx] = W[(by * 32 + ty + j * 8) * DIM + bx * 32 + tx];
        __syncthreads();
        #pragma unroll
        for (int j = 0; j < 4; ++j)
            T[(bx * 32 + ty + j * 8) * DIM + by * 32 + tx] = f2bf(tile[tx][ty + j * 8]);
    }
}

// ---------------- GEMM body: BK=32 DOUBLE-BUFFERED staging, 32 KB LDS (r10) ----------------
// Next slab's gld_lds issued BEFORE computing the current buffer; one barrier
// per K-step. __launch_bounds__(256,4) keeps regs <= 128/wave -> 4 blocks/CU.

__device__ __forceinline__ void gemm_body(int bx, int by,
        const unsigned short* __restrict__ A, const unsigned short* __restrict__ BT,
        unsigned short* __restrict__ Cb, const float* __restrict__ bias) {
    __shared__ __align__(16) unsigned short As[2][128][32];  // 16 KB
    __shared__ __align__(16) unsigned short Bs[2][128][32];  // 16 KB
    int tid = threadIdx.x;
    int wave = tid >> 6, lane = tid & 63;
    int row0 = bx * 128;
    int col0 = by * 128;
    int wm = (wave >> 1) * 64;
    int wn = (wave & 1) * 64;

    f32x4 acc[4][4] = {};

    int fr = lane & 15;
    int kg = (lane >> 4) * 8;

    #define STAGE32(buf, kt)                                                      \
        do {                                                                      \
            _Pragma("unroll")                                                     \
            for (int r_ = 0; r_ < 2; ++r_) {                                      \
                int idx_ = r_ * 256 + tid;                                        \
                int row_ = idx_ >> 2;                                             \
                int q_ = idx_ & 3;                                                \
                gld_lds16(A + (size_t)(row0 + row_) * DIM + (kt) * 32 + q_ * 8,   \
                          &As[buf][0][0] + idx_ * 8);                             \
                gld_lds16(BT + (size_t)(col0 + row_) * DIM + (kt) * 32 + q_ * 8,  \
                          &Bs[buf][0][0] + idx_ * 8);                             \
            }                                                                     \
        } while (0)

    STAGE32(0, 0);
    __syncthreads();

    int cur = 0;
    #pragma unroll
    for (int kt = 0; kt < 8; ++kt) {
        if (kt < 7) STAGE32(cur ^ 1, kt + 1);
        bf16x8 a_frag[4], b_frag[4];
        #pragma unroll
        for (int i = 0; i < 4; ++i) {
            a_frag[i] = *(const bf16x8*)(&As[cur][wm + i * 16 + fr][kg]);
            b_frag[i] = *(const bf16x8*)(&Bs[cur][wn + i * 16 + fr][kg]);
        }
        #pragma unroll
        for (int i = 0; i < 4; ++i)
            #pragma unroll
            for (int j = 0; j < 4; ++j)
                acc[i][j] = __builtin_amdgcn_mfma_f32_16x16x32_bf16(
                    a_frag[i], b_frag[j], acc[i][j], 0, 0, 0);
        if (kt < 7) { __syncthreads(); cur ^= 1; }
    }
    #undef STAGE32

    int rg = (lane >> 4) * 4;
    #pragma unroll
    for (int i = 0; i < 4; ++i) {
        #pragma unroll
        for (int j = 0; j < 4; ++j) {
            int n = col0 + wn + j * 16 + fr;
            float bv = bias ? bias[n] : 0.0f;
            #pragma unroll
            for (int r = 0; r < 4; ++r) {
                int m = row0 + wm + i * 16 + rg + r;
                Cb[(size_t)m * DIM + n] = f2bf(acc[i][j][r] + bv);
            }
        }
    }
}

__global__ __launch_bounds__(256, 4) void gemm_kernel(const unsigned short* __restrict__ A,
                                                      const unsigned short* __restrict__ BT,
                                                      unsigned short* __restrict__ Cb,
                                                      const float* __restrict__ bias) {
    int bx, by;
    xcd_pair(blockIdx.x, bx, by);
    gemm_body(bx, by, A, BT, Cb, bias);
}

// ---------------- combo2: projection GEMM + CSR fill (independent outputs) ----------------

__global__ __launch_bounds__(256, 4) void combo2(const unsigned short* __restrict__ A,
                                                 const unsigned short* __restrict__ BT,
                                                 unsigned short* __restrict__ Cb,
                                                 const float* __restrict__ bias,
                                                 const int* __restrict__ src,
                                                 const int* __restrict__ dst,
                                                 int* __restrict__ cursor,
                                                 int* __restrict__ csr) {
    int b = blockIdx.x;
    if (b < GEMM_BLOCKS) {
        int bx, by;
        xcd_pair(b, bx, by);
        gemm_body(bx, by, A, BT, Cb, bias);
    } else {
        int i = (b - GEMM_BLOCKS) * 256 + threadIdx.x;
        if (i < NEDGES) {
            int pos = atomicAdd(&cursor[dst[i]], 1);
            csr[pos] = src[i];
        }
    }
}

// ---------------- edge softmax + aggregation: in-wave el/er + PACKED f32x2 math --------
// One wave per dst node; 32 lanes per edge, 2 edges per iteration (proven
// r10 structure; edge assignment, shfl pattern, write mapping unchanged).
// NEW (r11): per-edge arithmetic packed into f32x2 (v_pk_fma_f32):
//   dot = 4 packed FMA + 1 horizontal add (was 8 scalar FMA)
//   acc = 4 packed FMA              (was 8 scalar FMA)
// r10 counters showed VALUBusy 57% > mem 41% -> VALU-leaning; this cuts
// per-edge VALU ~27%. (This packed math is r1's edge_acc, which was never
// the r1 bug -- the shfl-broadcast loop was.)

__global__ __launch_bounds__(256) void agg_kernel(const unsigned short* __restrict__ Hb,
                                                  const float* __restrict__ al,
                                                  const float* __restrict__ ar,
                                                  const int* __restrict__ rowptr,
                                                  const int* __restrict__ csr,
                                                  const float* __restrict__ bias,
                                                  float* __restrict__ outf,
                                                  unsigned short* __restrict__ outb) {
    int wave = threadIdx.x >> 6;
    int lane = threadIdx.x & 63;
    int v = blockIdx.x * 4 + wave;
    if (v >= NNODES) return;
    int sub = lane & 31;     // lane within half-wave
    int halfe = lane >> 5;   // which edge of the pair this half handles
    int c0 = sub * 8;        // dim offset (8 dims/lane)

    // attention vectors for this lane's 8 dims, as 4 f32x2 pairs
    f32x2 av[4], gv[4];
    #pragma unroll
    for (int j = 0; j < 4; ++j) {
        av[j] = *(const f32x2*)(al + c0 + 2 * j);
        gv[j] = *(const f32x2*)(ar + c0 + 2 * j);
    }

    // self row: both halves load (same cache lines) and derive el_v, er_v
    uint4 hw = *(const uint4*)(Hb + (size_t)v * DIM + c0);
    f32x2 hv[4] = { bfpair(hw.x), bfpair(hw.y), bfpair(hw.z), bfpair(hw.w) };
    f32x2 dl2 = hv[0] * av[0] + hv[1] * av[1] + hv[2] * av[2] + hv[3] * av[3];
    f32x2 dr2 = hv[0] * gv[0] + hv[1] * gv[1] + hv[2] * gv[2] + hv[3] * gv[3];
    float dl = dl2.x + dl2.y;
    float dr = dr2.x + dr2.y;
    dl += __shfl_xor(dl, 1, 64); dl += __shfl_xor(dl, 2, 64);
    dr += __shfl_xor(dr, 1, 64); dr += __shfl_xor(dr, 2, 64);
    float el_v = dl, er_v = dr;

    int beg = rowptr[v], end = rowptr[v + 1];

    float z = 0.0f;
    f32x2 acc2[4] = {};  // acc2[j] = dims (c0+2j, c0+2j+1)

    // self loop on half 0 only
    if (halfe == 0) {
        float ws = __expf(leaky(el_v + er_v));
        z = ws;
        f32x2 w2 = {ws, ws};
        #pragma unroll
        for (int j = 0; j < 4; ++j) acc2[j] = w2 * hv[j];
    }

    #pragma unroll 4
    for (int i = beg + halfe; i < end; i += 2) {
        int u = csr[i];
        uint4 h = *(const uint4*)(Hb + (size_t)u * DIM + c0);
        f32x2 h0 = bfpair(h.x), h1 = bfpair(h.y), h2 = bfpair(h.z), h3 = bfpair(h.w);
        f32x2 d2 = h0 * av[0] + h1 * av[1] + h2 * av[2] + h3 * av[3];
        float du = d2.x + d2.y;
        du += __shfl_xor(du, 1, 64);
        du += __shfl_xor(du, 2, 64);
        float e = leaky(du + er_v);
        float wi = __expf(e);
        z += wi;
        f32x2 w2 = {wi, wi};
        acc2[0] += w2 * h0;
        acc2[1] += w2 * h1;
        acc2[2] += w2 * h2;
        acc2[3] += w2 * h3;
    }

    // cross-half reduction: both halves end with full totals
    z += __shfl_xor(z, 32, 64);
    #pragma unroll
    for (int j = 0; j < 4; ++j) {
        acc2[j].x += __shfl_xor(acc2[j].x, 32, 64);
        acc2[j].y += __shfl_xor(acc2[j].y, 32, 64);
    }

    float inv = 1.0f / z;
    // each half stores 4 of the lane's 8 dims: half0 -> pairs{0,1}, half1 -> pairs{2,3}
    f32x2 pa = (halfe == 0) ? acc2[0] : acc2[2];
    f32x2 pb = (halfe == 0) ? acc2[1] : acc2[3];
    int o0 = c0 + halfe * 4;
    float4 b = *(const float4*)(bias + o0);
    float r0 = leaky(pa.x * inv + b.x);
    float r1 = leaky(pa.y * inv + b.y);
    float r2 = leaky(pb.x * inv + b.z);
    float r3 = leaky(pb.y * inv + b.w);
    if (outf) {
        float4 o = { r0, r1, r2, r3 };
        *(float4*)(outf + (size_t)v * DIM + o0) = o;
    } else {
        u16x4 o;
        o.x = f2bf(r0); o.y = f2bf(r1); o.z = f2bf(r2); o.w = f2bf(r3);
        *(u16x4*)(outb + (size_t)v * DIM + o0) = o;
    }
}

// ---------------- launch ----------------

static inline size_t align256(size_t x) { return (x + 255) & ~(size_t)255; }

extern "C" void kernel_launch(void* const* d_in, const int* in_sizes, int n_in,
                              void* d_out, int out_size, void* d_ws, size_t ws_size,
                              hipStream_t stream) {
    const float* feats  = (const float*)d_in[0];
    const int*   src    = (const int*)d_in[1];
    const int*   dst    = (const int*)d_in[2];
    const float* proj_W = (const float*)d_in[3];
    const float* proj_b = (const float*)d_in[4];
    const float* W1     = (const float*)d_in[5];
    const float* al1    = (const float*)d_in[6];
    const float* ar1    = (const float*)d_in[7];
    const float* b1     = (const float*)d_in[8];
    const float* W2     = (const float*)d_in[9];
    const float* al2    = (const float*)d_in[10];
    const float* ar2    = (const float*)d_in[11];
    const float* b2     = (const float*)d_in[12];
    float* out = (float*)d_out;

    uint8_t* w = (uint8_t*)d_ws;
    unsigned short* Abf = (unsigned short*)w; w += align256((size_t)MPAD * DIM * 2);
    unsigned short* Bbf = (unsigned short*)w; w += align256((size_t)MPAD * DIM * 2);
    unsigned short* Hb  = (unsigned short*)w; w += align256((size_t)MPAD * DIM * 2);
    unsigned short* WT  = (unsigned short*)w; w += align256((size_t)3 * DIM * DIM * 2);
    int* deg    = (int*)w;            w += align256((size_t)NNODES * 4);
    int* rowptr = (int*)w;            w += align256((size_t)(NNODES + 1) * 4);
    int* cursor = (int*)w;            w += align256((size_t)NNODES * 4);
    int* csr    = (int*)w;            w += align256((size_t)NEDGES * 4);
    int* bsum   = (int*)w;            w += align256((size_t)SCAN_BLOCKS * 4);
    int* boff   = (int*)w;            w += align256((size_t)SCAN_BLOCKS * 4);

    unsigned short* WT0 = WT;
    unsigned short* WT1 = WT + (size_t)DIM * DIM;
    unsigned short* WT2 = WT + (size_t)2 * DIM * DIM;

    const int node_wave_blocks = (NNODES + 3) / 4;  // one wave per node

    hipMemsetAsync(deg, 0, (size_t)NNODES * 4, stream);

    // count + feats->bf16 + weight transpose, one dispatch
    combo1<<<COUNT_BLOCKS + CVT_BLOCKS + TR_BLOCKS, 256, 0, stream>>>(
        dst, deg, feats, Abf, proj_W, W1, W2, WT);

    scanA_kernel<<<SCAN_BLOCKS, 256, 0, stream>>>(deg, bsum);
    scanB_kernel<<<1, 256, 0, stream>>>(bsum, boff, rowptr);
    scanC_kernel<<<SCAN_BLOCKS, 256, 0, stream>>>(deg, boff, rowptr, cursor);

    // projection gemm + CSR fill, one dispatch
    combo2<<<GEMM_BLOCKS + COUNT_BLOCKS, 256, 0, stream>>>(
        Abf, WT0, Bbf, proj_b, src, dst, cursor, csr);

    // layer 1: Hb = Bbf @ W1 ; agg (in-wave el/er) -> Abf (bf16)
    gemm_kernel<<<GEMM_BLOCKS, 256, 0, stream>>>(Bbf, WT1, Hb, nullptr);
    agg_kernel<<<node_wave_blocks, 256, 0, stream>>>(Hb, al1, ar1, rowptr, csr, b1,
                                                     nullptr, Abf);

    // layer 2: Hb = Abf @ W2 ; agg (in-wave el/er) -> out (fp32)
    gemm_kernel<<<GEMM_BLOCKS, 256, 0, stream>>>(Abf, WT2, Hb, nullptr);
    agg_kernel<<<node_wave_blocks, 256, 0, stream>>>(Hb, al2, ar2, rowptr, csr, b2,
                                                     out, nullptr);
}